// Round 1
// baseline (851.801 us; speedup 1.0000x reference)
//
#include <hip/hip_runtime.h>
#include <hip/hip_bf16.h>

// Problem constants
#define NB 128     // batch
#define AA 128     // conv1 out channels
#define BB 32      // capsule types
#define CC 10      // classes
#define KK 6       // primary grid
#define DD 16      // pose dim
#define NN 1152    // B*K*K
#define H1 14      // conv1 out spatial
#define CH2 544    // B*D+B

// ---------------- conv1: (128,3,32,32) -> (128,128,14,14), 5x5 stride 2 ----------------
__global__ void k_conv1(const float* __restrict__ x, const float* __restrict__ w,
                        float* __restrict__ h) {
    int idx = blockIdx.x * 256 + threadIdx.x;
    if (idx >= NB * AA * H1 * H1) return;
    int ox = idx % H1; int t = idx / H1;
    int oy = t % H1; t /= H1;
    int oc = t % AA; int b = t / AA;
    const float* xb = x + b * (3 * 32 * 32);
    const float* wc = w + oc * 75;
    float acc = 0.f;
    int iy = oy * 2, ix = ox * 2;
#pragma unroll
    for (int ic = 0; ic < 3; ++ic) {
#pragma unroll
        for (int ky = 0; ky < 5; ++ky) {
            const float* xr = xb + ic * 1024 + (iy + ky) * 32 + ix;
            const float* wr = wc + ic * 25 + ky * 5;
#pragma unroll
            for (int kx = 0; kx < 5; ++kx) acc = fmaf(xr[kx], wr[kx], acc);
        }
    }
    h[idx] = acc;
}

// ---------------- bn1 stats: per-channel mean/var over (b, 14, 14) ----------------
__global__ void k_bnstats1(const float* __restrict__ h, const float* __restrict__ g,
                           const float* __restrict__ be, float* __restrict__ bn1) {
    int c = blockIdx.x;
    int tid = threadIdx.x;
    float s = 0.f, s2 = 0.f;
    for (int j = tid; j < NB * 196; j += 256) {
        int b = j / 196, hw = j % 196;
        float v = h[(b * AA + c) * 196 + hw];
        s += v; s2 += v * v;
    }
#pragma unroll
    for (int o = 32; o > 0; o >>= 1) { s += __shfl_down(s, o); s2 += __shfl_down(s2, o); }
    __shared__ float ls[4], lq[4];
    int lane = tid & 63, wid = tid >> 6;
    if (lane == 0) { ls[wid] = s; lq[wid] = s2; }
    __syncthreads();
    if (tid == 0) {
        s = ls[0] + ls[1] + ls[2] + ls[3];
        s2 = lq[0] + lq[1] + lq[2] + lq[3];
        const float n = (float)(NB * 196);
        float mu = s / n;
        float var = s2 / n - mu * mu;
        float sc = g[c] * rsqrtf(var + 1e-5f);
        bn1[c] = sc;
        bn1[AA + c] = be[c] - mu * sc;
    }
}

// ---------------- apply bn1 + relu ----------------
__global__ void k_bnrelu(const float* __restrict__ h, const float* __restrict__ bn1,
                         float* __restrict__ hbn) {
    int idx = blockIdx.x * 256 + threadIdx.x;
    if (idx >= NB * AA * 196) return;
    int c = (idx / 196) % AA;
    hbn[idx] = fmaxf(h[idx] * bn1[c] + bn1[AA + c], 0.f);
}

// ---------------- conv2: (128,128,14,14) -> (128,544,6,6), 3x3 stride 2 ----------------
// one thread per (b, oc, oy), computes a row of 6 outputs
__global__ void k_conv2(const float* __restrict__ hbn, const float* __restrict__ w,
                        float* __restrict__ pc) {
    int idx = blockIdx.x * 256 + threadIdx.x;
    if (idx >= NB * CH2 * KK) return;
    int oy = idx % KK; int t = idx / KK;
    int oc = t % CH2; int b = t / CH2;
    float acc[6] = {0.f, 0.f, 0.f, 0.f, 0.f, 0.f};
    const float* wb = w + oc * (AA * 9);
    const float* hb = hbn + b * (AA * 196) + (oy * 2) * 14;
    for (int ic = 0; ic < AA; ++ic) {
        const float* hr = hb + ic * 196;
        const float* wr = wb + ic * 9;
#pragma unroll
        for (int ky = 0; ky < 3; ++ky) {
            const float* r = hr + ky * 14;
            float wk0 = wr[ky * 3 + 0], wk1 = wr[ky * 3 + 1], wk2 = wr[ky * 3 + 2];
            float v[13];
#pragma unroll
            for (int j = 0; j < 13; ++j) v[j] = r[j];
#pragma unroll
            for (int ox = 0; ox < 6; ++ox)
                acc[ox] = fmaf(v[ox * 2], wk0,
                          fmaf(v[ox * 2 + 1], wk1,
                          fmaf(v[ox * 2 + 2], wk2, acc[ox])));
        }
    }
    float* out = pc + (b * CH2 + oc) * 36 + oy * 6;
#pragma unroll
    for (int ox = 0; ox < 6; ++ox) out[ox] = acc[ox];
}

// ---------------- bn stats for poses (per i over b,d,6,6) and a (per i over b,6,6) ----------------
__global__ void k_bnstats2(const float* __restrict__ pc,
                           const float* __restrict__ bna_g, const float* __restrict__ bna_b,
                           const float* __restrict__ bnp_g, const float* __restrict__ bnp_b,
                           float* __restrict__ bn2) {
    int blk = blockIdx.x;
    int tid = threadIdx.x;
    float s = 0.f, s2 = 0.f;
    if (blk < 32) {  // pose group i
        int i = blk;
        for (int j = tid; j < NB * DD * 36; j += 256) {
            int b = j / (DD * 36); int rem = j % (DD * 36);
            int d = rem / 36; int xy = rem % 36;
            float v = pc[((b * CH2) + i * DD + d) * 36 + xy];
            s += v; s2 += v * v;
        }
    } else {  // a channel i
        int i = blk - 32;
        for (int j = tid; j < NB * 36; j += 256) {
            int b = j / 36, xy = j % 36;
            float v = pc[((b * CH2) + BB * DD + i) * 36 + xy];
            s += v; s2 += v * v;
        }
    }
#pragma unroll
    for (int o = 32; o > 0; o >>= 1) { s += __shfl_down(s, o); s2 += __shfl_down(s2, o); }
    __shared__ float ls[4], lq[4];
    int lane = tid & 63, wid = tid >> 6;
    if (lane == 0) { ls[wid] = s; lq[wid] = s2; }
    __syncthreads();
    if (tid == 0) {
        s = ls[0] + ls[1] + ls[2] + ls[3];
        s2 = lq[0] + lq[1] + lq[2] + lq[3];
        if (blk < 32) {
            int i = blk;
            const float n = (float)(NB * DD * 36);
            float mu = s / n, var = s2 / n - mu * mu;
            float sc = bnp_g[i] * rsqrtf(var + 1e-5f);
            bn2[i] = sc; bn2[32 + i] = bnp_b[i] - mu * sc;
        } else {
            int i = blk - 32;
            const float n = (float)(NB * 36);
            float mu = s / n, var = s2 / n - mu * mu;
            float sc = bna_g[i] * rsqrtf(var + 1e-5f);
            bn2[64 + i] = sc; bn2[96 + i] = bna_b[i] - mu * sc;
        }
    }
}

// ---------------- transform: pc -> poses_bn (b,n,16) and a_i (b,n) ----------------
__global__ void k_transform(const float* __restrict__ pc, const float* __restrict__ bn2,
                            float* __restrict__ pose, float* __restrict__ ai) {
    int idx = blockIdx.x * 256 + threadIdx.x;  // (b, n)
    if (idx >= NB * NN) return;
    int n = idx % NN, b = idx / NN;
    int i = n / 36, xy = n % 36;
    float sc = bn2[i], sh = bn2[32 + i];
    float* pd = pose + (size_t)idx * 16;
    const float* ps = pc + ((b * CH2) + i * DD) * 36 + xy;
#pragma unroll
    for (int d = 0; d < 16; ++d) pd[d] = ps[d * 36] * sc + sh;
    float va = pc[((b * CH2) + BB * DD + i) * 36 + xy] * bn2[64 + i] + bn2[96 + i];
    ai[idx] = 1.f / (1.f + expf(-va));
}

// ---------------- VB stats: per (b,c) reduce Nj, S1[d]=Sum Ra*V, S2[d]=Sum Ra*V^2 ----------------
template <int FIRST>
__global__ void k_stats(const float* __restrict__ pose, const float* __restrict__ ai,
                        const float* __restrict__ R, const float* __restrict__ Wij,
                        float* __restrict__ Nj, float* __restrict__ S1, float* __restrict__ S2) {
    int bc = blockIdx.x;
    int c = bc % CC, b = bc / CC;
    int tid = threadIdx.x;
    float s0 = 0.f;
    float s1[16], s2[16];
#pragma unroll
    for (int k = 0; k < 16; ++k) { s1[k] = 0.f; s2[k] = 0.f; }
    for (int n = tid; n < NN; n += 256) {
        int i = n / 36, xy = n % 36;
        const float4* pp = reinterpret_cast<const float4*>(pose + ((size_t)b * NN + n) * 16);
        const float4* wp = reinterpret_cast<const float4*>(Wij + (((size_t)i * CC + c) * 36 + xy) * 16);
        alignas(16) float P[16], W[16];
        *reinterpret_cast<float4*>(&P[0])  = pp[0];
        *reinterpret_cast<float4*>(&P[4])  = pp[1];
        *reinterpret_cast<float4*>(&P[8])  = pp[2];
        *reinterpret_cast<float4*>(&P[12]) = pp[3];
        *reinterpret_cast<float4*>(&W[0])  = wp[0];
        *reinterpret_cast<float4*>(&W[4])  = wp[1];
        *reinterpret_cast<float4*>(&W[8])  = wp[2];
        *reinterpret_cast<float4*>(&W[12]) = wp[3];
        float wgt = ai[b * NN + n];
        if (FIRST) wgt *= 0.1f;
        else wgt *= R[((size_t)(b * CC + c)) * NN + n];
        s0 += wgt;
#pragma unroll
        for (int p = 0; p < 4; ++p) {
#pragma unroll
            for (int r = 0; r < 4; ++r) {
                float v = W[p * 4 + 0] * P[0 + r] + W[p * 4 + 1] * P[4 + r] +
                          W[p * 4 + 2] * P[8 + r] + W[p * 4 + 3] * P[12 + r];
                int d = p * 4 + r;
                float wv = wgt * v;
                s1[d] += wv;
                s2[d] = fmaf(wv, v, s2[d]);
            }
        }
    }
    // reduce 33 values across block
#pragma unroll
    for (int o = 32; o > 0; o >>= 1) {
        s0 += __shfl_down(s0, o);
#pragma unroll
        for (int k = 0; k < 16; ++k) {
            s1[k] += __shfl_down(s1[k], o);
            s2[k] += __shfl_down(s2[k], o);
        }
    }
    __shared__ float red[4][33];
    int lane = tid & 63, wid = tid >> 6;
    if (lane == 0) {
        red[wid][0] = s0;
#pragma unroll
        for (int k = 0; k < 16; ++k) { red[wid][1 + k] = s1[k]; red[wid][17 + k] = s2[k]; }
    }
    __syncthreads();
    if (tid < 33) {
        float v = red[0][tid] + red[1][tid] + red[2][tid] + red[3][tid];
        if (tid == 0) Nj[bc] = v + 1e-8f;
        else if (tid < 17) S1[bc * 16 + (tid - 1)] = v;
        else S2[bc * 16 + (tid - 17)] = v;
    }
}

// ---------------- digamma (args always >= 1.0 here) ----------------
__device__ __forceinline__ float digammaf_(float x) {
    float r = 0.f;
    while (x < 6.f) { r -= 1.f / x; x += 1.f; }
    float xi = 1.f / x;
    float xi2 = xi * xi;
    return r + logf(x) - 0.5f * xi -
           xi2 * (0.0833333333f - xi2 * (0.0083333333f - xi2 * 0.0039682540f));
}

// ---------------- expectations: per (b,c) compute m, G=0.5*nu/Psi, lnp base (and logits) ----------------
template <int LOGITS>
__global__ void k_expect(const float* __restrict__ Nj, const float* __restrict__ S1,
                         const float* __restrict__ S2, float* __restrict__ m,
                         float* __restrict__ G, float* __restrict__ base,
                         float* __restrict__ logits) {
    int b = blockIdx.x;
    int c = threadIdx.x;  // 64 threads, 10 active
    __shared__ float alph[CC];
    float nj = 0.f;
    if (c < CC) {
        nj = Nj[b * CC + c];
        alph[c] = 1.f + nj;
    }
    __syncthreads();
    if (c < CC) {
        int bc = b * CC + c;
        float asum = 0.f;
#pragma unroll
        for (int k = 0; k < CC; ++k) asum += alph[k];
        float kappa = 1.f + nj;
        float nu = 17.f + nj;   // NU0 = D+1 = 17
        float S0 = nj - 1e-8f;
        float elnlam = 16.f * 0.69314718056f;  // D*ln2
        for (int d = 0; d < 16; ++d) {
            float s1 = S1[bc * 16 + d], s2v = S2[bc * 16 + d];
            float xbar = s1 / nj;
            float sig = (s2v - 2.f * xbar * s1 + xbar * xbar * S0) / nj;
            float Psi = 1.f + nj * sig + (nj / kappa) * xbar * xbar;
            elnlam += digammaf_(0.5f * (nu + 1.f - (float)(d + 1))) - logf(Psi);
            m[bc * 16 + d] = nj * xbar / kappa;
            G[bc * 16 + d] = 0.5f * nu / Psi;
        }
        float elnpi = digammaf_(1.f + nj) - digammaf_(asum);
        float lb = elnpi + 0.5f * elnlam;
        if (LOGITS) logits[bc] = lb;
        // base = E_lnpi + 0.5 E_lnLam - 0.5 D ln(2pi) - 0.5 D / kappa
        base[bc] = lb - 8.f * 1.83787706641f - 8.f / kappa;
    }
}

// ---------------- R update: per (b,n), softmax over c of base - Sum dm^2*G ----------------
__global__ void k_update(const float* __restrict__ pose, const float* __restrict__ Wij,
                         const float* __restrict__ m, const float* __restrict__ G,
                         const float* __restrict__ base, float* __restrict__ R) {
    int b = blockIdx.y;
    int n = blockIdx.x * 256 + threadIdx.x;
    __shared__ float sm[CC][16], sG[CC][16], sb[CC];
    for (int j = threadIdx.x; j < CC * 16; j += 256) {
        sm[j / 16][j % 16] = m[b * CC * 16 + j];
        sG[j / 16][j % 16] = G[b * CC * 16 + j];
    }
    if (threadIdx.x < CC) sb[threadIdx.x] = base[b * CC + threadIdx.x];
    __syncthreads();
    if (n >= NN) return;
    const float4* pp = reinterpret_cast<const float4*>(pose + ((size_t)b * NN + n) * 16);
    alignas(16) float P[16];
    *reinterpret_cast<float4*>(&P[0])  = pp[0];
    *reinterpret_cast<float4*>(&P[4])  = pp[1];
    *reinterpret_cast<float4*>(&P[8])  = pp[2];
    *reinterpret_cast<float4*>(&P[12]) = pp[3];
    int i = n / 36, xy = n % 36;
    float lnp[CC];
    float mx = -1e30f;
#pragma unroll
    for (int c = 0; c < CC; ++c) {
        const float4* wp = reinterpret_cast<const float4*>(Wij + (((size_t)i * CC + c) * 36 + xy) * 16);
        alignas(16) float W[16];
        *reinterpret_cast<float4*>(&W[0])  = wp[0];
        *reinterpret_cast<float4*>(&W[4])  = wp[1];
        *reinterpret_cast<float4*>(&W[8])  = wp[2];
        *reinterpret_cast<float4*>(&W[12]) = wp[3];
        float q = 0.f;
#pragma unroll
        for (int p = 0; p < 4; ++p) {
#pragma unroll
            for (int r = 0; r < 4; ++r) {
                float v = W[p * 4 + 0] * P[0 + r] + W[p * 4 + 1] * P[4 + r] +
                          W[p * 4 + 2] * P[8 + r] + W[p * 4 + 3] * P[12 + r];
                float dm = v - sm[c][p * 4 + r];
                q = fmaf(dm * dm, sG[c][p * 4 + r], q);
            }
        }
        lnp[c] = sb[c] - q;
        mx = fmaxf(mx, lnp[c]);
    }
    float ssum = 0.f;
#pragma unroll
    for (int c = 0; c < CC; ++c) { lnp[c] = expf(lnp[c] - mx); ssum += lnp[c]; }
    float inv = 1.f / ssum;
#pragma unroll
    for (int c = 0; c < CC; ++c) R[((size_t)(b * CC + c)) * NN + n] = lnp[c] * inv;
}

// ---------------- final: BN over batch per class + sigmoid ----------------
__global__ void k_final(const float* __restrict__ logits, float* __restrict__ out) {
    int c = blockIdx.x;      // 10 blocks
    int b = threadIdx.x;     // 128 threads
    float v = logits[b * CC + c];
    float s = v, s2 = v * v;
#pragma unroll
    for (int o = 32; o > 0; o >>= 1) { s += __shfl_down(s, o); s2 += __shfl_down(s2, o); }
    __shared__ float ls[2], lq[2];
    int lane = b & 63, wid = b >> 6;
    if (lane == 0) { ls[wid] = s; lq[wid] = s2; }
    __syncthreads();
    float mu = (ls[0] + ls[1]) * (1.f / 128.f);
    float var = (lq[0] + lq[1]) * (1.f / 128.f) - mu * mu;
    out[b * CC + c] = 1.f / (1.f + expf(-(v - mu) * rsqrtf(var + 1e-5f)));
}

extern "C" void kernel_launch(void* const* d_in, const int* in_sizes, int n_in,
                              void* d_out, int out_size, void* d_ws, size_t ws_size,
                              hipStream_t stream) {
    (void)in_sizes; (void)n_in; (void)out_size; (void)ws_size;
    const float* x       = (const float*)d_in[0];
    const float* conv1_w = (const float*)d_in[1];
    const float* bn1_g   = (const float*)d_in[2];
    const float* bn1_b   = (const float*)d_in[3];
    const float* prim_w  = (const float*)d_in[4];
    const float* bna_g   = (const float*)d_in[5];
    const float* bna_b   = (const float*)d_in[6];
    const float* bnp_g   = (const float*)d_in[7];
    const float* bnp_b   = (const float*)d_in[8];
    const float* Wij     = (const float*)d_in[9];

    float* ws = (float*)d_ws;
    float* h      = ws + 0;          // 3,211,264
    float* hbn    = ws + 3211264;    // 3,211,264
    float* pc     = ws + 6422528;    // 2,506,752
    float* pose   = ws + 8929280;    // 2,359,296
    float* ai     = ws + 11288576;   // 147,456
    float* R      = ws + 11436032;   // 1,474,560
    float* bn1    = ws + 12910592;   // 256
    float* bn2    = ws + 12910848;   // 128
    float* Nj     = ws + 12910976;   // 1,280
    float* S1     = ws + 12912256;   // 20,480
    float* S2     = ws + 12932736;   // 20,480
    float* m      = ws + 12953216;   // 20,480
    float* G      = ws + 12973696;   // 20,480
    float* base   = ws + 12994176;   // 1,280
    float* logits = ws + 12995456;   // 1,280
    float* out    = (float*)d_out;

    k_conv1<<<12544, 256, 0, stream>>>(x, conv1_w, h);
    k_bnstats1<<<128, 256, 0, stream>>>(h, bn1_g, bn1_b, bn1);
    k_bnrelu<<<12544, 256, 0, stream>>>(h, bn1, hbn);
    k_conv2<<<1632, 256, 0, stream>>>(hbn, prim_w, pc);
    k_bnstats2<<<64, 256, 0, stream>>>(pc, bna_g, bna_b, bnp_g, bnp_b, bn2);
    k_transform<<<576, 256, 0, stream>>>(pc, bn2, pose, ai);

    // routing iter 0 (R implicit = 1/C)
    k_stats<1><<<1280, 256, 0, stream>>>(pose, ai, R, Wij, Nj, S1, S2);
    k_expect<0><<<128, 64, 0, stream>>>(Nj, S1, S2, m, G, base, logits);
    k_update<<<dim3(5, 128), 256, 0, stream>>>(pose, Wij, m, G, base, R);
    // iter 1
    k_stats<0><<<1280, 256, 0, stream>>>(pose, ai, R, Wij, Nj, S1, S2);
    k_expect<0><<<128, 64, 0, stream>>>(Nj, S1, S2, m, G, base, logits);
    k_update<<<dim3(5, 128), 256, 0, stream>>>(pose, Wij, m, G, base, R);
    // iter 2 (stats + expectations only)
    k_stats<0><<<1280, 256, 0, stream>>>(pose, ai, R, Wij, Nj, S1, S2);
    k_expect<1><<<128, 64, 0, stream>>>(Nj, S1, S2, m, G, base, logits);

    k_final<<<10, 128, 0, stream>>>(logits, out);
}

// Round 4
// 618.771 us; speedup vs baseline: 1.3766x; 1.3766x over previous
//
#include <hip/hip_runtime.h>
#include <hip/hip_bf16.h>

// Problem constants
#define NB 128     // batch
#define AA 128     // conv1 out channels
#define BB 32      // capsule types
#define CC 10      // classes
#define KK 6       // primary grid
#define DD 16      // pose dim
#define NN 1152    // B*K*K
#define H1 14      // conv1 out spatial
#define CH2 544    // B*D+B

// ---------------- conv1: (128,3,32,32) -> (128,128,14,14), 5x5 stride 2 ----------------
__global__ void k_conv1(const float* __restrict__ x, const float* __restrict__ w,
                        float* __restrict__ h) {
    int idx = blockIdx.x * 256 + threadIdx.x;
    if (idx >= NB * AA * H1 * H1) return;
    int ox = idx % H1; int t = idx / H1;
    int oy = t % H1; t /= H1;
    int oc = t % AA; int b = t / AA;
    const float* xb = x + b * (3 * 32 * 32);
    const float* wc = w + oc * 75;
    float acc = 0.f;
    int iy = oy * 2, ix = ox * 2;
#pragma unroll
    for (int ic = 0; ic < 3; ++ic) {
#pragma unroll
        for (int ky = 0; ky < 5; ++ky) {
            const float* xr = xb + ic * 1024 + (iy + ky) * 32 + ix;
            const float* wr = wc + ic * 25 + ky * 5;
#pragma unroll
            for (int kx = 0; kx < 5; ++kx) acc = fmaf(xr[kx], wr[kx], acc);
        }
    }
    h[idx] = acc;
}

// ---------------- bn1 stats: per-channel mean/var over (b, 14, 14) ----------------
__global__ void k_bnstats1(const float* __restrict__ h, const float* __restrict__ g,
                           const float* __restrict__ be, float* __restrict__ bn1) {
    int c = blockIdx.x;
    int tid = threadIdx.x;
    float s = 0.f, s2 = 0.f;
    for (int j = tid; j < NB * 196; j += 256) {
        int b = j / 196, hw = j % 196;
        float v = h[(b * AA + c) * 196 + hw];
        s += v; s2 += v * v;
    }
#pragma unroll
    for (int o = 32; o > 0; o >>= 1) { s += __shfl_down(s, o); s2 += __shfl_down(s2, o); }
    __shared__ float ls[4], lq[4];
    int lane = tid & 63, wid = tid >> 6;
    if (lane == 0) { ls[wid] = s; lq[wid] = s2; }
    __syncthreads();
    if (tid == 0) {
        s = ls[0] + ls[1] + ls[2] + ls[3];
        s2 = lq[0] + lq[1] + lq[2] + lq[3];
        const float n = (float)(NB * 196);
        float mu = s / n;
        float var = s2 / n - mu * mu;
        float sc = g[c] * rsqrtf(var + 1e-5f);
        bn1[c] = sc;
        bn1[AA + c] = be[c] - mu * sc;
    }
}

// ---------------- apply bn1 + relu ----------------
__global__ void k_bnrelu(const float* __restrict__ h, const float* __restrict__ bn1,
                         float* __restrict__ hbn) {
    int idx = blockIdx.x * 256 + threadIdx.x;
    if (idx >= NB * AA * 196) return;
    int c = (idx / 196) % AA;
    hbn[idx] = fmaxf(h[idx] * bn1[c] + bn1[AA + c], 0.f);
}

// ---------------- conv2 (LDS-tiled): (128,128,14,14) -> (128,544,6,6), 3x3 stride 2 ----
// grid (5, 128): blockIdx.x = 128-oc tile, blockIdx.y = b. 256 threads = 4 waves.
// wave g owns 3x3 output block at (oy0,ox0) = ((g>>1)*3, (g&1)*3); lane owns oc_l, oc_l+64.
#define TOC 128
#define ICC 8
__global__ __launch_bounds__(256, 3) void k_conv2(const float* __restrict__ hbn,
                                                  const float* __restrict__ w,
                                                  float* __restrict__ pc) {
    __shared__ float sIn[ICC][14][16];          // 7 KB, padded rows
    __shared__ float sW[TOC][ICC * 9 + 1];      // 37.4 KB, stride 73 -> conflict-free
    int b = blockIdx.y;
    int oc0 = blockIdx.x * TOC;
    int tid = threadIdx.x;
    int lane = tid & 63;
    int g = tid >> 6;
    int oy0 = (g >> 1) * 3, ox0 = (g & 1) * 3;
    int iy0 = oy0 * 2, ix0 = ox0 * 2;
    float acc[2][9];
#pragma unroll
    for (int h = 0; h < 2; ++h)
#pragma unroll
        for (int j = 0; j < 9; ++j) acc[h][j] = 0.f;
    const float* hb = hbn + b * (AA * 196);

    for (int ic0 = 0; ic0 < AA; ic0 += ICC) {
        // stage input chunk (coalesced)
        for (int j = tid; j < ICC * 196; j += 256) {
            int ic = j / 196, rem = j % 196;
            sIn[ic][rem / 14][rem % 14] = hb[(ic0 + ic) * 196 + rem];
        }
        // stage weight chunk (coalesced within oc rows)
        for (int j = tid; j < TOC * (ICC * 9); j += 256) {
            int o = j / (ICC * 9), e = j % (ICC * 9);
            int og = oc0 + o;
            sW[o][e] = (og < CH2) ? w[og * (AA * 9) + ic0 * 9 + e] : 0.f;
        }
        __syncthreads();
#pragma unroll
        for (int ic = 0; ic < ICC; ++ic) {
            float p[7][7];
#pragma unroll
            for (int r = 0; r < 7; ++r)
#pragma unroll
                for (int c2 = 0; c2 < 7; ++c2)
                    p[r][c2] = sIn[ic][iy0 + r][ix0 + c2];
#pragma unroll
            for (int h = 0; h < 2; ++h) {
                float wr[9];
#pragma unroll
                for (int k = 0; k < 9; ++k) wr[k] = sW[lane + 64 * h][ic * 9 + k];
#pragma unroll
                for (int oyl = 0; oyl < 3; ++oyl)
#pragma unroll
                    for (int oxl = 0; oxl < 3; ++oxl) {
                        float s = acc[h][oyl * 3 + oxl];
#pragma unroll
                        for (int ky = 0; ky < 3; ++ky)
#pragma unroll
                            for (int kx = 0; kx < 3; ++kx)
                                s = fmaf(p[oyl * 2 + ky][oxl * 2 + kx], wr[ky * 3 + kx], s);
                        acc[h][oyl * 3 + oxl] = s;
                    }
            }
        }
        __syncthreads();
    }
#pragma unroll
    for (int h = 0; h < 2; ++h) {
        int oc = oc0 + lane + 64 * h;
        if (oc < CH2) {
            float* out = pc + ((size_t)b * CH2 + oc) * 36;
#pragma unroll
            for (int oyl = 0; oyl < 3; ++oyl)
#pragma unroll
                for (int oxl = 0; oxl < 3; ++oxl)
                    out[(oy0 + oyl) * 6 + ox0 + oxl] = acc[h][oyl * 3 + oxl];
        }
    }
}

// ---------------- bn stats for poses (per i over b,d,6,6) and a (per i over b,6,6) ----------------
__global__ void k_bnstats2(const float* __restrict__ pc,
                           const float* __restrict__ bna_g, const float* __restrict__ bna_b,
                           const float* __restrict__ bnp_g, const float* __restrict__ bnp_b,
                           float* __restrict__ bn2) {
    int blk = blockIdx.x;
    int tid = threadIdx.x;
    float s = 0.f, s2 = 0.f;
    if (blk < 32) {  // pose group i
        int i = blk;
        for (int j = tid; j < NB * DD * 36; j += 256) {
            int b = j / (DD * 36); int rem = j % (DD * 36);
            int d = rem / 36; int xy = rem % 36;
            float v = pc[((b * CH2) + i * DD + d) * 36 + xy];
            s += v; s2 += v * v;
        }
    } else {  // a channel i
        int i = blk - 32;
        for (int j = tid; j < NB * 36; j += 256) {
            int b = j / 36, xy = j % 36;
            float v = pc[((b * CH2) + BB * DD + i) * 36 + xy];
            s += v; s2 += v * v;
        }
    }
#pragma unroll
    for (int o = 32; o > 0; o >>= 1) { s += __shfl_down(s, o); s2 += __shfl_down(s2, o); }
    __shared__ float ls[4], lq[4];
    int lane = tid & 63, wid = tid >> 6;
    if (lane == 0) { ls[wid] = s; lq[wid] = s2; }
    __syncthreads();
    if (tid == 0) {
        s = ls[0] + ls[1] + ls[2] + ls[3];
        s2 = lq[0] + lq[1] + lq[2] + lq[3];
        if (blk < 32) {
            int i = blk;
            const float n = (float)(NB * DD * 36);
            float mu = s / n, var = s2 / n - mu * mu;
            float sc = bnp_g[i] * rsqrtf(var + 1e-5f);
            bn2[i] = sc; bn2[32 + i] = bnp_b[i] - mu * sc;
        } else {
            int i = blk - 32;
            const float n = (float)(NB * 36);
            float mu = s / n, var = s2 / n - mu * mu;
            float sc = bna_g[i] * rsqrtf(var + 1e-5f);
            bn2[64 + i] = sc; bn2[96 + i] = bna_b[i] - mu * sc;
        }
    }
}

// ---------------- transform: pc -> poses_bn (b,n,16) and a_i (b,n) ----------------
__global__ void k_transform(const float* __restrict__ pc, const float* __restrict__ bn2,
                            float* __restrict__ pose, float* __restrict__ ai) {
    int idx = blockIdx.x * 256 + threadIdx.x;  // (b, n)
    if (idx >= NB * NN) return;
    int n = idx % NN, b = idx / NN;
    int i = n / 36, xy = n % 36;
    float sc = bn2[i], sh = bn2[32 + i];
    float* pd = pose + (size_t)idx * 16;
    const float* ps = pc + ((b * CH2) + i * DD) * 36 + xy;
#pragma unroll
    for (int d = 0; d < 16; ++d) pd[d] = ps[d * 36] * sc + sh;
    float va = pc[((b * CH2) + BB * DD + i) * 36 + xy] * bn2[64 + i] + bn2[96 + i];
    ai[idx] = 1.f / (1.f + expf(-va));
}

// ---------------- VB stats: per (b,c) reduce Nj, S1[d]=Sum Ra*V, S2[d]=Sum Ra*V^2 ----------------
template <int FIRST>
__global__ void k_stats(const float* __restrict__ pose, const float* __restrict__ ai,
                        const float* __restrict__ R, const float* __restrict__ Wij,
                        float* __restrict__ Nj, float* __restrict__ S1, float* __restrict__ S2) {
    int bc = blockIdx.x;
    int c = bc % CC, b = bc / CC;
    int tid = threadIdx.x;
    float s0 = 0.f;
    float s1[16], s2[16];
#pragma unroll
    for (int k = 0; k < 16; ++k) { s1[k] = 0.f; s2[k] = 0.f; }
    for (int n = tid; n < NN; n += 256) {
        int i = n / 36, xy = n % 36;
        const float4* pp = reinterpret_cast<const float4*>(pose + ((size_t)b * NN + n) * 16);
        const float4* wp = reinterpret_cast<const float4*>(Wij + (((size_t)i * CC + c) * 36 + xy) * 16);
        alignas(16) float P[16], W[16];
        *reinterpret_cast<float4*>(&P[0])  = pp[0];
        *reinterpret_cast<float4*>(&P[4])  = pp[1];
        *reinterpret_cast<float4*>(&P[8])  = pp[2];
        *reinterpret_cast<float4*>(&P[12]) = pp[3];
        *reinterpret_cast<float4*>(&W[0])  = wp[0];
        *reinterpret_cast<float4*>(&W[4])  = wp[1];
        *reinterpret_cast<float4*>(&W[8])  = wp[2];
        *reinterpret_cast<float4*>(&W[12]) = wp[3];
        float wgt = ai[b * NN + n];
        if (FIRST) wgt *= 0.1f;
        else wgt *= R[((size_t)(b * CC + c)) * NN + n];
        s0 += wgt;
#pragma unroll
        for (int p = 0; p < 4; ++p) {
#pragma unroll
            for (int r = 0; r < 4; ++r) {
                float v = W[p * 4 + 0] * P[0 + r] + W[p * 4 + 1] * P[4 + r] +
                          W[p * 4 + 2] * P[8 + r] + W[p * 4 + 3] * P[12 + r];
                int d = p * 4 + r;
                float wv = wgt * v;
                s1[d] += wv;
                s2[d] = fmaf(wv, v, s2[d]);
            }
        }
    }
    // reduce 33 values across block
#pragma unroll
    for (int o = 32; o > 0; o >>= 1) {
        s0 += __shfl_down(s0, o);
#pragma unroll
        for (int k = 0; k < 16; ++k) {
            s1[k] += __shfl_down(s1[k], o);
            s2[k] += __shfl_down(s2[k], o);
        }
    }
    __shared__ float red[4][33];
    int lane = tid & 63, wid = tid >> 6;
    if (lane == 0) {
        red[wid][0] = s0;
#pragma unroll
        for (int k = 0; k < 16; ++k) { red[wid][1 + k] = s1[k]; red[wid][17 + k] = s2[k]; }
    }
    __syncthreads();
    if (tid < 33) {
        float v = red[0][tid] + red[1][tid] + red[2][tid] + red[3][tid];
        if (tid == 0) Nj[bc] = v + 1e-8f;
        else if (tid < 17) S1[bc * 16 + (tid - 1)] = v;
        else S2[bc * 16 + (tid - 17)] = v;
    }
}

// ---------------- digamma (args always >= 1.0 here) ----------------
__device__ __forceinline__ float digammaf_(float x) {
    float r = 0.f;
    while (x < 6.f) { r -= 1.f / x; x += 1.f; }
    float xi = 1.f / x;
    float xi2 = xi * xi;
    return r + logf(x) - 0.5f * xi -
           xi2 * (0.0833333333f - xi2 * (0.0083333333f - xi2 * 0.0039682540f));
}

// ---------------- expectations: per (b,c) compute m, G=0.5*nu/Psi, lnp base (and logits) ----------------
template <int LOGITS>
__global__ void k_expect(const float* __restrict__ Nj, const float* __restrict__ S1,
                         const float* __restrict__ S2, float* __restrict__ m,
                         float* __restrict__ G, float* __restrict__ base,
                         float* __restrict__ logits) {
    int b = blockIdx.x;
    int c = threadIdx.x;  // 64 threads, 10 active
    __shared__ float alph[CC];
    float nj = 0.f;
    if (c < CC) {
        nj = Nj[b * CC + c];
        alph[c] = 1.f + nj;
    }
    __syncthreads();
    if (c < CC) {
        int bc = b * CC + c;
        float asum = 0.f;
#pragma unroll
        for (int k = 0; k < CC; ++k) asum += alph[k];
        float kappa = 1.f + nj;
        float nu = 17.f + nj;   // NU0 = D+1 = 17
        float S0 = nj - 1e-8f;
        float elnlam = 16.f * 0.69314718056f;  // D*ln2
        for (int d = 0; d < 16; ++d) {
            float s1 = S1[bc * 16 + d], s2v = S2[bc * 16 + d];
            float xbar = s1 / nj;
            float sig = (s2v - 2.f * xbar * s1 + xbar * xbar * S0) / nj;
            float Psi = 1.f + nj * sig + (nj / kappa) * xbar * xbar;
            elnlam += digammaf_(0.5f * (nu + 1.f - (float)(d + 1))) - logf(Psi);
            m[bc * 16 + d] = nj * xbar / kappa;
            G[bc * 16 + d] = 0.5f * nu / Psi;
        }
        float elnpi = digammaf_(1.f + nj) - digammaf_(asum);
        float lb = elnpi + 0.5f * elnlam;
        if (LOGITS) logits[bc] = lb;
        // base = E_lnpi + 0.5 E_lnLam - 0.5 D ln(2pi) - 0.5 D / kappa
        base[bc] = lb - 8.f * 1.83787706641f - 8.f / kappa;
    }
}

// ---------------- R update: per (b,n), softmax over c of base - Sum dm^2*G ----------------
__global__ void k_update(const float* __restrict__ pose, const float* __restrict__ Wij,
                         const float* __restrict__ m, const float* __restrict__ G,
                         const float* __restrict__ base, float* __restrict__ R) {
    int b = blockIdx.y;
    int n = blockIdx.x * 256 + threadIdx.x;
    __shared__ float sm[CC][16], sG[CC][16], sb[CC];
    for (int j = threadIdx.x; j < CC * 16; j += 256) {
        sm[j / 16][j % 16] = m[b * CC * 16 + j];
        sG[j / 16][j % 16] = G[b * CC * 16 + j];
    }
    if (threadIdx.x < CC) sb[threadIdx.x] = base[b * CC + threadIdx.x];
    __syncthreads();
    if (n >= NN) return;
    const float4* pp = reinterpret_cast<const float4*>(pose + ((size_t)b * NN + n) * 16);
    alignas(16) float P[16];
    *reinterpret_cast<float4*>(&P[0])  = pp[0];
    *reinterpret_cast<float4*>(&P[4])  = pp[1];
    *reinterpret_cast<float4*>(&P[8])  = pp[2];
    *reinterpret_cast<float4*>(&P[12]) = pp[3];
    int i = n / 36, xy = n % 36;
    float lnp[CC];
    float mx = -1e30f;
#pragma unroll
    for (int c = 0; c < CC; ++c) {
        const float4* wp = reinterpret_cast<const float4*>(Wij + (((size_t)i * CC + c) * 36 + xy) * 16);
        alignas(16) float W[16];
        *reinterpret_cast<float4*>(&W[0])  = wp[0];
        *reinterpret_cast<float4*>(&W[4])  = wp[1];
        *reinterpret_cast<float4*>(&W[8])  = wp[2];
        *reinterpret_cast<float4*>(&W[12]) = wp[3];
        float q = 0.f;
#pragma unroll
        for (int p = 0; p < 4; ++p) {
#pragma unroll
            for (int r = 0; r < 4; ++r) {
                float v = W[p * 4 + 0] * P[0 + r] + W[p * 4 + 1] * P[4 + r] +
                          W[p * 4 + 2] * P[8 + r] + W[p * 4 + 3] * P[12 + r];
                float dm = v - sm[c][p * 4 + r];
                q = fmaf(dm * dm, sG[c][p * 4 + r], q);
            }
        }
        lnp[c] = sb[c] - q;
        mx = fmaxf(mx, lnp[c]);
    }
    float ssum = 0.f;
#pragma unroll
    for (int c = 0; c < CC; ++c) { lnp[c] = expf(lnp[c] - mx); ssum += lnp[c]; }
    float inv = 1.f / ssum;
#pragma unroll
    for (int c = 0; c < CC; ++c) R[((size_t)(b * CC + c)) * NN + n] = lnp[c] * inv;
}

// ---------------- final: BN over batch per class + sigmoid ----------------
__global__ void k_final(const float* __restrict__ logits, float* __restrict__ out) {
    int c = blockIdx.x;      // 10 blocks
    int b = threadIdx.x;     // 128 threads
    float v = logits[b * CC + c];
    float s = v, s2 = v * v;
#pragma unroll
    for (int o = 32; o > 0; o >>= 1) { s += __shfl_down(s, o); s2 += __shfl_down(s2, o); }
    __shared__ float ls[2], lq[2];
    int lane = b & 63, wid = b >> 6;
    if (lane == 0) { ls[wid] = s; lq[wid] = s2; }
    __syncthreads();
    float mu = (ls[0] + ls[1]) * (1.f / 128.f);
    float var = (lq[0] + lq[1]) * (1.f / 128.f) - mu * mu;
    out[b * CC + c] = 1.f / (1.f + expf(-(v - mu) * rsqrtf(var + 1e-5f)));
}

extern "C" void kernel_launch(void* const* d_in, const int* in_sizes, int n_in,
                              void* d_out, int out_size, void* d_ws, size_t ws_size,
                              hipStream_t stream) {
    (void)in_sizes; (void)n_in; (void)out_size; (void)ws_size;
    const float* x       = (const float*)d_in[0];
    const float* conv1_w = (const float*)d_in[1];
    const float* bn1_g   = (const float*)d_in[2];
    const float* bn1_b   = (const float*)d_in[3];
    const float* prim_w  = (const float*)d_in[4];
    const float* bna_g   = (const float*)d_in[5];
    const float* bna_b   = (const float*)d_in[6];
    const float* bnp_g   = (const float*)d_in[7];
    const float* bnp_b   = (const float*)d_in[8];
    const float* Wij     = (const float*)d_in[9];

    float* ws = (float*)d_ws;
    float* h      = ws + 0;          // 3,211,264
    float* hbn    = ws + 3211264;    // 3,211,264
    float* pc     = ws + 6422528;    // 2,506,752
    float* pose   = ws + 8929280;    // 2,359,296
    float* ai     = ws + 11288576;   // 147,456
    float* R      = ws + 11436032;   // 1,474,560
    float* bn1    = ws + 12910592;   // 256
    float* bn2    = ws + 12910848;   // 128
    float* Nj     = ws + 12910976;   // 1,280
    float* S1     = ws + 12912256;   // 20,480
    float* S2     = ws + 12932736;   // 20,480
    float* m      = ws + 12953216;   // 20,480
    float* G      = ws + 12973696;   // 20,480
    float* base   = ws + 12994176;   // 1,280
    float* logits = ws + 12995456;   // 1,280
    float* out    = (float*)d_out;

    k_conv1<<<12544, 256, 0, stream>>>(x, conv1_w, h);
    k_bnstats1<<<128, 256, 0, stream>>>(h, bn1_g, bn1_b, bn1);
    k_bnrelu<<<12544, 256, 0, stream>>>(h, bn1, hbn);
    k_conv2<<<dim3(5, 128), 256, 0, stream>>>(hbn, prim_w, pc);
    k_bnstats2<<<64, 256, 0, stream>>>(pc, bna_g, bna_b, bnp_g, bnp_b, bn2);
    k_transform<<<576, 256, 0, stream>>>(pc, bn2, pose, ai);

    // routing iter 0 (R implicit = 1/C)
    k_stats<1><<<1280, 256, 0, stream>>>(pose, ai, R, Wij, Nj, S1, S2);
    k_expect<0><<<128, 64, 0, stream>>>(Nj, S1, S2, m, G, base, logits);
    k_update<<<dim3(5, 128), 256, 0, stream>>>(pose, Wij, m, G, base, R);
    // iter 1
    k_stats<0><<<1280, 256, 0, stream>>>(pose, ai, R, Wij, Nj, S1, S2);
    k_expect<0><<<128, 64, 0, stream>>>(Nj, S1, S2, m, G, base, logits);
    k_update<<<dim3(5, 128), 256, 0, stream>>>(pose, Wij, m, G, base, R);
    // iter 2 (stats + expectations only)
    k_stats<0><<<1280, 256, 0, stream>>>(pose, ai, R, Wij, Nj, S1, S2);
    k_expect<1><<<128, 64, 0, stream>>>(Nj, S1, S2, m, G, base, logits);

    k_final<<<10, 128, 0, stream>>>(logits, out);
}

// Round 6
// 530.321 us; speedup vs baseline: 1.6062x; 1.1668x over previous
//
#include <hip/hip_runtime.h>
#include <hip/hip_bf16.h>

// Problem constants
#define NB 128     // batch
#define AA 128     // conv1 out channels
#define BB 32      // capsule types
#define CC 10      // classes
#define KK 6       // primary grid
#define DD 16      // pose dim
#define NN 1152    // B*K*K
#define H1 14      // conv1 out spatial
#define CH2 544    // B*D+B

// ---------------- weight transpose: w[oc][ic*9+k] -> wT[ic*9+k][oc] ----------------
__global__ void k_wT(const float* __restrict__ w, float* __restrict__ wT) {
    int o = blockIdx.x * 256 + threadIdx.x;
    if (o >= CH2 * AA * 9) return;
    int oc = o % CH2, ick = o / CH2;
    wT[o] = w[oc * (AA * 9) + ick];
}

// ---------------- conv1: (128,3,32,32) -> (128,128,14,14), 5x5 stride 2 ----------------
// one thread per (b, oc, oy): computes a full row of 14 outputs
__global__ void k_conv1(const float* __restrict__ x, const float* __restrict__ w,
                        float* __restrict__ h) {
    int idx = blockIdx.x * 256 + threadIdx.x;
    if (idx >= NB * AA * H1) return;
    int oy = idx % H1; int t = idx / H1;
    int oc = t % AA; int b = t / AA;
    float acc[14];
#pragma unroll
    for (int j = 0; j < 14; ++j) acc[j] = 0.f;
    const float* xb = x + b * 3072;
    const float* wc = w + oc * 75;
#pragma unroll
    for (int ic = 0; ic < 3; ++ic) {
#pragma unroll
        for (int ky = 0; ky < 5; ++ky) {
            const float* xr = xb + ic * 1024 + (2 * oy + ky) * 32;
            float row[32];
#pragma unroll
            for (int q = 0; q < 8; ++q) {
                float4 v = *reinterpret_cast<const float4*>(xr + q * 4);
                row[q * 4 + 0] = v.x; row[q * 4 + 1] = v.y;
                row[q * 4 + 2] = v.z; row[q * 4 + 3] = v.w;
            }
            float w0 = wc[ic * 25 + ky * 5 + 0];
            float w1 = wc[ic * 25 + ky * 5 + 1];
            float w2 = wc[ic * 25 + ky * 5 + 2];
            float w3 = wc[ic * 25 + ky * 5 + 3];
            float w4 = wc[ic * 25 + ky * 5 + 4];
#pragma unroll
            for (int ox = 0; ox < 14; ++ox) {
                float s = acc[ox];
                s = fmaf(row[2 * ox + 0], w0, s);
                s = fmaf(row[2 * ox + 1], w1, s);
                s = fmaf(row[2 * ox + 2], w2, s);
                s = fmaf(row[2 * ox + 3], w3, s);
                s = fmaf(row[2 * ox + 4], w4, s);
                acc[ox] = s;
            }
        }
    }
    float* out = h + (size_t)idx * 14;
#pragma unroll
    for (int ox = 0; ox < 14; ++ox) out[ox] = acc[ox];
}

// ---------------- bn1 stats: per-channel mean/var over (b, 14, 14) ----------------
__global__ void k_bnstats1(const float* __restrict__ h, const float* __restrict__ g,
                           const float* __restrict__ be, float* __restrict__ bn1) {
    int c = blockIdx.x;
    int tid = threadIdx.x;
    float s = 0.f, s2 = 0.f;
    for (int j = tid; j < NB * 196; j += 256) {
        int b = j / 196, hw = j % 196;
        float v = h[(b * AA + c) * 196 + hw];
        s += v; s2 += v * v;
    }
#pragma unroll
    for (int o = 32; o > 0; o >>= 1) { s += __shfl_down(s, o); s2 += __shfl_down(s2, o); }
    __shared__ float ls[4], lq[4];
    int lane = tid & 63, wid = tid >> 6;
    if (lane == 0) { ls[wid] = s; lq[wid] = s2; }
    __syncthreads();
    if (tid == 0) {
        s = ls[0] + ls[1] + ls[2] + ls[3];
        s2 = lq[0] + lq[1] + lq[2] + lq[3];
        const float n = (float)(NB * 196);
        float mu = s / n;
        float var = s2 / n - mu * mu;
        float sc = g[c] * rsqrtf(var + 1e-5f);
        bn1[c] = sc;
        bn1[AA + c] = be[c] - mu * sc;
    }
}

// ---------------- apply bn1 + relu ----------------
__global__ void k_bnrelu(const float* __restrict__ h, const float* __restrict__ bn1,
                         float* __restrict__ hbn) {
    int idx = blockIdx.x * 256 + threadIdx.x;
    if (idx >= NB * AA * 196) return;
    int c = (idx / 196) % AA;
    hbn[idx] = fmaxf(h[idx] * bn1[c] + bn1[AA + c], 0.f);
}

// ---------------- conv2: (128,128,14,14) -> (128,544,6,6), 3x3 stride 2 ----------------
// grid (5, 128, 2): oc-tile of 128, batch, spatial half (3 output rows).
// 256 threads = 4 waves; wave w handles ics [w*8 .. w*8+8) of each 32-ic chunk.
// lane owns ocs (oc0+2*lane, oc0+2*lane+1), computes all 18 outputs of the half.
// Cross-wave (ic) partial sums reduced through LDS at the end.
__global__ __launch_bounds__(256, 4) void k_conv2(const float* __restrict__ hbn,
                                                  const float* __restrict__ wT,
                                                  float* __restrict__ pc) {
    __shared__ __align__(16) float sIn[32][7][16];  // 14,336 B
    __shared__ float sRed[128][19];                 //  9,728 B
    const int b = blockIdx.y;
    const int hh = blockIdx.z;            // spatial half: output rows 3*hh..3*hh+2
    const int oc0 = blockIdx.x * 128;
    const int tid = threadIdx.x;
    const int lane = tid & 63;
    const int wv = tid >> 6;
    const int y0 = 6 * hh;                // input rows y0..y0+6
    const int myoc = oc0 + 2 * lane;
    const bool valid = myoc < CH2;        // pair (myoc, myoc+1) valid together
    const int ocl = valid ? 2 * lane : 0; // clamped offset (avoid OOB loads)

    float acc[2][18];
#pragma unroll
    for (int p = 0; p < 2; ++p)
#pragma unroll
        for (int s = 0; s < 18; ++s) acc[p][s] = 0.f;

    const float* hb = hbn + (size_t)b * (AA * 196);

#pragma unroll 1
    for (int chunk = 0; chunk < 4; ++chunk) {
        // stage 32 ics x 7 rows x 14 cols
        for (int j = tid; j < 32 * 7 * 14; j += 256) {
            int c = j % 14; int t2 = j / 14; int r = t2 % 7; int ic = t2 / 7;
            sIn[ic][r][c] = hb[(chunk * 32 + ic) * 196 + (y0 + r) * 14 + c];
        }
        __syncthreads();
#pragma unroll 1
        for (int icl = 0; icl < 8; ++icl) {
            const int icL = wv * 8 + icl;          // LDS ic index
            const int icG = chunk * 32 + icL;      // global ic
            // weights (coalesced float2 per k)
            float w0[9], w1[9];
            const float* wp = wT + (size_t)(icG * 9) * CH2 + oc0 + ocl;
#pragma unroll
            for (int k = 0; k < 9; ++k) {
                float2 wv2 = *reinterpret_cast<const float2*>(wp + k * CH2);
                w0[k] = valid ? wv2.x : 0.f;
                w1[k] = valid ? wv2.y : 0.f;
            }
#pragma unroll
            for (int r = 0; r < 3; ++r) {
                float rw[3][13];
#pragma unroll
                for (int rr = 0; rr < 3; ++rr) {
                    const float* src = &sIn[icL][2 * r + rr][0];
                    float4 a = *reinterpret_cast<const float4*>(src);
                    float4 bq = *reinterpret_cast<const float4*>(src + 4);
                    float4 cq = *reinterpret_cast<const float4*>(src + 8);
                    rw[rr][0] = a.x;  rw[rr][1] = a.y;  rw[rr][2] = a.z;  rw[rr][3] = a.w;
                    rw[rr][4] = bq.x; rw[rr][5] = bq.y; rw[rr][6] = bq.z; rw[rr][7] = bq.w;
                    rw[rr][8] = cq.x; rw[rr][9] = cq.y; rw[rr][10] = cq.z; rw[rr][11] = cq.w;
                    rw[rr][12] = src[12];
                }
#pragma unroll
                for (int xx = 0; xx < 6; ++xx) {
                    float s0 = acc[0][r * 6 + xx], s1 = acc[1][r * 6 + xx];
#pragma unroll
                    for (int ky = 0; ky < 3; ++ky) {
#pragma unroll
                        for (int kx = 0; kx < 3; ++kx) {
                            float pv = rw[ky][2 * xx + kx];
                            s0 = fmaf(pv, w0[ky * 3 + kx], s0);
                            s1 = fmaf(pv, w1[ky * 3 + kx], s1);
                        }
                    }
                    acc[0][r * 6 + xx] = s0; acc[1][r * 6 + xx] = s1;
                }
            }
        }
        __syncthreads();
    }

    // reduce 4 ic-partials across waves via LDS
    int ro = 2 * lane;
    if (wv == 0) {
#pragma unroll
        for (int s = 0; s < 18; ++s) { sRed[ro][s] = acc[0][s]; sRed[ro + 1][s] = acc[1][s]; }
    }
    __syncthreads();
#pragma unroll 1
    for (int w = 1; w < 4; ++w) {
        if (wv == w) {
#pragma unroll
            for (int s = 0; s < 18; ++s) { sRed[ro][s] += acc[0][s]; sRed[ro + 1][s] += acc[1][s]; }
        }
        __syncthreads();
    }
    // write out 128 ocs x 18 spatial (= 2304 = 9*256)
#pragma unroll
    for (int e = 0; e < 9; ++e) {
        int flat = tid + 256 * e;
        int oc = flat / 18, s = flat % 18;
        if (oc0 + oc < CH2)
            pc[((size_t)b * CH2 + oc0 + oc) * 36 + 18 * hh + s] = sRed[oc][s];
    }
}

// ---------------- bn stats for poses (per i over b,d,6,6) and a (per i over b,6,6) ----------------
__global__ void k_bnstats2(const float* __restrict__ pc,
                           const float* __restrict__ bna_g, const float* __restrict__ bna_b,
                           const float* __restrict__ bnp_g, const float* __restrict__ bnp_b,
                           float* __restrict__ bn2) {
    int blk = blockIdx.x;
    int tid = threadIdx.x;
    float s = 0.f, s2 = 0.f;
    if (blk < 32) {  // pose group i
        int i = blk;
        for (int j = tid; j < NB * DD * 36; j += 256) {
            int b = j / (DD * 36); int rem = j % (DD * 36);
            int d = rem / 36; int xy = rem % 36;
            float v = pc[((b * CH2) + i * DD + d) * 36 + xy];
            s += v; s2 += v * v;
        }
    } else {  // a channel i
        int i = blk - 32;
        for (int j = tid; j < NB * 36; j += 256) {
            int b = j / 36, xy = j % 36;
            float v = pc[((b * CH2) + BB * DD + i) * 36 + xy];
            s += v; s2 += v * v;
        }
    }
#pragma unroll
    for (int o = 32; o > 0; o >>= 1) { s += __shfl_down(s, o); s2 += __shfl_down(s2, o); }
    __shared__ float ls[4], lq[4];
    int lane = tid & 63, wid = tid >> 6;
    if (lane == 0) { ls[wid] = s; lq[wid] = s2; }
    __syncthreads();
    if (tid == 0) {
        s = ls[0] + ls[1] + ls[2] + ls[3];
        s2 = lq[0] + lq[1] + lq[2] + lq[3];
        if (blk < 32) {
            int i = blk;
            const float n = (float)(NB * DD * 36);
            float mu = s / n, var = s2 / n - mu * mu;
            float sc = bnp_g[i] * rsqrtf(var + 1e-5f);
            bn2[i] = sc; bn2[32 + i] = bnp_b[i] - mu * sc;
        } else {
            int i = blk - 32;
            const float n = (float)(NB * 36);
            float mu = s / n, var = s2 / n - mu * mu;
            float sc = bna_g[i] * rsqrtf(var + 1e-5f);
            bn2[64 + i] = sc; bn2[96 + i] = bna_b[i] - mu * sc;
        }
    }
}

// ---------------- transform: pc -> poses_bn (b,n,16) and a_i (b,n) ----------------
__global__ void k_transform(const float* __restrict__ pc, const float* __restrict__ bn2,
                            float* __restrict__ pose, float* __restrict__ ai) {
    int idx = blockIdx.x * 256 + threadIdx.x;  // (b, n)
    if (idx >= NB * NN) return;
    int n = idx % NN, b = idx / NN;
    int i = n / 36, xy = n % 36;
    float sc = bn2[i], sh = bn2[32 + i];
    float* pd = pose + (size_t)idx * 16;
    const float* ps = pc + ((b * CH2) + i * DD) * 36 + xy;
#pragma unroll
    for (int d = 0; d < 16; ++d) pd[d] = ps[d * 36] * sc + sh;
    float va = pc[((b * CH2) + BB * DD + i) * 36 + xy] * bn2[64 + i] + bn2[96 + i];
    ai[idx] = 1.f / (1.f + expf(-va));
}

// ---------------- VB stats: one wave per (b,c); Nj, S1[d]=Sum Ra*V, S2[d]=Sum Ra*V^2 ----
template <int FIRST>
__global__ void k_stats(const float* __restrict__ pose, const float* __restrict__ ai,
                        const float* __restrict__ R, const float* __restrict__ Wij,
                        float* __restrict__ Nj, float* __restrict__ S1, float* __restrict__ S2) {
    int bc = blockIdx.x * 4 + (threadIdx.x >> 6);   // 320 blocks * 4 waves = 1280
    int lane = threadIdx.x & 63;
    int c = bc % CC, b = bc / CC;
    float s0 = 0.f;
    float s1[16], s2[16];
#pragma unroll
    for (int k = 0; k < 16; ++k) { s1[k] = 0.f; s2[k] = 0.f; }
    for (int n = lane; n < NN; n += 64) {
        int i = n / 36, xy = n % 36;
        const float4* pp = reinterpret_cast<const float4*>(pose + ((size_t)b * NN + n) * 16);
        const float4* wp = reinterpret_cast<const float4*>(Wij + (((size_t)i * CC + c) * 36 + xy) * 16);
        alignas(16) float P[16], W[16];
        *reinterpret_cast<float4*>(&P[0])  = pp[0];
        *reinterpret_cast<float4*>(&P[4])  = pp[1];
        *reinterpret_cast<float4*>(&P[8])  = pp[2];
        *reinterpret_cast<float4*>(&P[12]) = pp[3];
        *reinterpret_cast<float4*>(&W[0])  = wp[0];
        *reinterpret_cast<float4*>(&W[4])  = wp[1];
        *reinterpret_cast<float4*>(&W[8])  = wp[2];
        *reinterpret_cast<float4*>(&W[12]) = wp[3];
        float wgt = ai[b * NN + n];
        if (FIRST) wgt *= 0.1f;
        else wgt *= R[((size_t)(b * CC + c)) * NN + n];
        s0 += wgt;
#pragma unroll
        for (int p = 0; p < 4; ++p) {
#pragma unroll
            for (int r = 0; r < 4; ++r) {
                float v = W[p * 4 + 0] * P[0 + r] + W[p * 4 + 1] * P[4 + r] +
                          W[p * 4 + 2] * P[8 + r] + W[p * 4 + 3] * P[12 + r];
                int d = p * 4 + r;
                float wv = wgt * v;
                s1[d] += wv;
                s2[d] = fmaf(wv, v, s2[d]);
            }
        }
    }
    // wave-level reduce of 33 values
#pragma unroll
    for (int o = 32; o > 0; o >>= 1) {
        s0 += __shfl_down(s0, o);
#pragma unroll
        for (int k = 0; k < 16; ++k) {
            s1[k] += __shfl_down(s1[k], o);
            s2[k] += __shfl_down(s2[k], o);
        }
    }
    if (lane == 0) {
        Nj[bc] = s0 + 1e-8f;
#pragma unroll
        for (int k = 0; k < 16; ++k) { S1[bc * 16 + k] = s1[k]; S2[bc * 16 + k] = s2[k]; }
    }
}

// ---------------- digamma (args always >= 1.0 here) ----------------
__device__ __forceinline__ float digammaf_(float x) {
    float r = 0.f;
    while (x < 6.f) { r -= 1.f / x; x += 1.f; }
    float xi = 1.f / x;
    float xi2 = xi * xi;
    return r + logf(x) - 0.5f * xi -
           xi2 * (0.0833333333f - xi2 * (0.0083333333f - xi2 * 0.0039682540f));
}

// ---------------- expectations: per (b,c) compute m, G=0.5*nu/Psi, lnp base (and logits) ----------------
template <int LOGITS>
__global__ void k_expect(const float* __restrict__ Nj, const float* __restrict__ S1,
                         const float* __restrict__ S2, float* __restrict__ m,
                         float* __restrict__ G, float* __restrict__ base,
                         float* __restrict__ logits) {
    int b = blockIdx.x;
    int c = threadIdx.x;  // 64 threads, 10 active
    __shared__ float alph[CC];
    float nj = 0.f;
    if (c < CC) {
        nj = Nj[b * CC + c];
        alph[c] = 1.f + nj;
    }
    __syncthreads();
    if (c < CC) {
        int bc = b * CC + c;
        float asum = 0.f;
#pragma unroll
        for (int k = 0; k < CC; ++k) asum += alph[k];
        float kappa = 1.f + nj;
        float nu = 17.f + nj;   // NU0 = D+1 = 17
        float S0 = nj - 1e-8f;
        float elnlam = 16.f * 0.69314718056f;  // D*ln2
        for (int d = 0; d < 16; ++d) {
            float s1 = S1[bc * 16 + d], s2v = S2[bc * 16 + d];
            float xbar = s1 / nj;
            float sig = (s2v - 2.f * xbar * s1 + xbar * xbar * S0) / nj;
            float Psi = 1.f + nj * sig + (nj / kappa) * xbar * xbar;
            elnlam += digammaf_(0.5f * (nu + 1.f - (float)(d + 1))) - logf(Psi);
            m[bc * 16 + d] = nj * xbar / kappa;
            G[bc * 16 + d] = 0.5f * nu / Psi;
        }
        float elnpi = digammaf_(1.f + nj) - digammaf_(asum);
        float lb = elnpi + 0.5f * elnlam;
        if (LOGITS) logits[bc] = lb;
        // base = E_lnpi + 0.5 E_lnLam - 0.5 D ln(2pi) - 0.5 D / kappa
        base[bc] = lb - 8.f * 1.83787706641f - 8.f / kappa;
    }
}

// ---------------- R update: per (b,n), softmax over c of base - Sum dm^2*G ----------------
__global__ void k_update(const float* __restrict__ pose, const float* __restrict__ Wij,
                         const float* __restrict__ m, const float* __restrict__ G,
                         const float* __restrict__ base, float* __restrict__ R) {
    int b = blockIdx.y;
    int n = blockIdx.x * 256 + threadIdx.x;
    __shared__ float sm[CC][16], sG[CC][16], sb[CC];
    for (int j = threadIdx.x; j < CC * 16; j += 256) {
        sm[j / 16][j % 16] = m[b * CC * 16 + j];
        sG[j / 16][j % 16] = G[b * CC * 16 + j];
    }
    if (threadIdx.x < CC) sb[threadIdx.x] = base[b * CC + threadIdx.x];
    __syncthreads();
    if (n >= NN) return;
    const float4* pp = reinterpret_cast<const float4*>(pose + ((size_t)b * NN + n) * 16);
    alignas(16) float P[16];
    *reinterpret_cast<float4*>(&P[0])  = pp[0];
    *reinterpret_cast<float4*>(&P[4])  = pp[1];
    *reinterpret_cast<float4*>(&P[8])  = pp[2];
    *reinterpret_cast<float4*>(&P[12]) = pp[3];
    int i = n / 36, xy = n % 36;
    float lnp[CC];
    float mx = -1e30f;
#pragma unroll
    for (int c = 0; c < CC; ++c) {
        const float4* wp = reinterpret_cast<const float4*>(Wij + (((size_t)i * CC + c) * 36 + xy) * 16);
        alignas(16) float W[16];
        *reinterpret_cast<float4*>(&W[0])  = wp[0];
        *reinterpret_cast<float4*>(&W[4])  = wp[1];
        *reinterpret_cast<float4*>(&W[8])  = wp[2];
        *reinterpret_cast<float4*>(&W[12]) = wp[3];
        float q = 0.f;
#pragma unroll
        for (int p = 0; p < 4; ++p) {
#pragma unroll
            for (int r = 0; r < 4; ++r) {
                float v = W[p * 4 + 0] * P[0 + r] + W[p * 4 + 1] * P[4 + r] +
                          W[p * 4 + 2] * P[8 + r] + W[p * 4 + 3] * P[12 + r];
                float dm = v - sm[c][p * 4 + r];
                q = fmaf(dm * dm, sG[c][p * 4 + r], q);
            }
        }
        lnp[c] = sb[c] - q;
        mx = fmaxf(mx, lnp[c]);
    }
    float ssum = 0.f;
#pragma unroll
    for (int c = 0; c < CC; ++c) { lnp[c] = expf(lnp[c] - mx); ssum += lnp[c]; }
    float inv = 1.f / ssum;
#pragma unroll
    for (int c = 0; c < CC; ++c) R[((size_t)(b * CC + c)) * NN + n] = lnp[c] * inv;
}

// ---------------- final: BN over batch per class + sigmoid ----------------
__global__ void k_final(const float* __restrict__ logits, float* __restrict__ out) {
    int c = blockIdx.x;      // 10 blocks
    int b = threadIdx.x;     // 128 threads
    float v = logits[b * CC + c];
    float s = v, s2 = v * v;
#pragma unroll
    for (int o = 32; o > 0; o >>= 1) { s += __shfl_down(s, o); s2 += __shfl_down(s2, o); }
    __shared__ float ls[2], lq[2];
    int lane = b & 63, wid = b >> 6;
    if (lane == 0) { ls[wid] = s; lq[wid] = s2; }
    __syncthreads();
    float mu = (ls[0] + ls[1]) * (1.f / 128.f);
    float var = (lq[0] + lq[1]) * (1.f / 128.f) - mu * mu;
    out[b * CC + c] = 1.f / (1.f + expf(-(v - mu) * rsqrtf(var + 1e-5f)));
}

extern "C" void kernel_launch(void* const* d_in, const int* in_sizes, int n_in,
                              void* d_out, int out_size, void* d_ws, size_t ws_size,
                              hipStream_t stream) {
    (void)in_sizes; (void)n_in; (void)out_size; (void)ws_size;
    const float* x       = (const float*)d_in[0];
    const float* conv1_w = (const float*)d_in[1];
    const float* bn1_g   = (const float*)d_in[2];
    const float* bn1_b   = (const float*)d_in[3];
    const float* prim_w  = (const float*)d_in[4];
    const float* bna_g   = (const float*)d_in[5];
    const float* bna_b   = (const float*)d_in[6];
    const float* bnp_g   = (const float*)d_in[7];
    const float* bnp_b   = (const float*)d_in[8];
    const float* Wij     = (const float*)d_in[9];

    float* ws = (float*)d_ws;
    float* h      = ws + 0;          // 3,211,264
    float* hbn    = ws + 3211264;    // 3,211,264
    float* pc     = ws + 6422528;    // 2,506,752
    float* pose   = ws + 8929280;    // 2,359,296
    float* ai     = ws + 11288576;   // 147,456
    float* R      = ws + 11436032;   // 1,474,560
    float* bn1    = ws + 12910592;   // 256
    float* bn2    = ws + 12910848;   // 128
    float* Nj     = ws + 12910976;   // 1,280
    float* S1     = ws + 12912256;   // 20,480
    float* S2     = ws + 12932736;   // 20,480
    float* m      = ws + 12953216;   // 20,480
    float* G      = ws + 12973696;   // 20,480
    float* base   = ws + 12994176;   // 1,280
    float* logits = ws + 12995456;   // 1,280
    float* out    = (float*)d_out;
    // wT (544*1152 = 626,688 floats) aliases R: R is only written (k_update) and
    // read (k_stats<0>) AFTER conv2 has completed; k_stats<1> ignores R.
    float* wT = R;

    k_wT<<<2449, 256, 0, stream>>>(prim_w, wT);
    k_conv1<<<896, 256, 0, stream>>>(x, conv1_w, h);
    k_bnstats1<<<128, 256, 0, stream>>>(h, bn1_g, bn1_b, bn1);
    k_bnrelu<<<12544, 256, 0, stream>>>(h, bn1, hbn);
    k_conv2<<<dim3(5, 128, 2), 256, 0, stream>>>(hbn, wT, pc);
    k_bnstats2<<<64, 256, 0, stream>>>(pc, bna_g, bna_b, bnp_g, bnp_b, bn2);
    k_transform<<<576, 256, 0, stream>>>(pc, bn2, pose, ai);

    // routing iter 0 (R implicit = 1/C)
    k_stats<1><<<320, 256, 0, stream>>>(pose, ai, R, Wij, Nj, S1, S2);
    k_expect<0><<<128, 64, 0, stream>>>(Nj, S1, S2, m, G, base, logits);
    k_update<<<dim3(5, 128), 256, 0, stream>>>(pose, Wij, m, G, base, R);
    // iter 1
    k_stats<0><<<320, 256, 0, stream>>>(pose, ai, R, Wij, Nj, S1, S2);
    k_expect<0><<<128, 64, 0, stream>>>(Nj, S1, S2, m, G, base, logits);
    k_update<<<dim3(5, 128), 256, 0, stream>>>(pose, Wij, m, G, base, R);
    // iter 2 (stats + expectations only)
    k_stats<0><<<320, 256, 0, stream>>>(pose, ai, R, Wij, Nj, S1, S2);
    k_expect<1><<<128, 64, 0, stream>>>(Nj, S1, S2, m, G, base, logits);

    k_final<<<10, 128, 0, stream>>>(logits, out);
}

// Round 7
// 322.606 us; speedup vs baseline: 2.6404x; 1.6439x over previous
//
#include <hip/hip_runtime.h>
#include <hip/hip_bf16.h>

// Problem constants
#define NB 128     // batch
#define AA 128     // conv1 out channels
#define BB 32      // capsule types
#define CC 10      // classes
#define KK 6       // primary grid
#define DD 16      // pose dim
#define NN 1152    // B*K*K
#define H1 14      // conv1 out spatial
#define CH2 544    // B*D+B
#define NG 4608    // GEMM N = NB*36
#define KG 1152    // GEMM K = 128*9
#define MG 576     // GEMM M padded (544 -> 9*64)

typedef short bfrag8 __attribute__((ext_vector_type(8)));   // 8 bf16 (4 VGPRs)
typedef float facc4 __attribute__((ext_vector_type(4)));    // 4 fp32 acc

__device__ __forceinline__ unsigned short f2bf(float f) {   // RNE f32->bf16
    unsigned u = __float_as_uint(f);
    u += 0x7FFF + ((u >> 16) & 1);
    return (unsigned short)(u >> 16);
}
__device__ __forceinline__ float bf2f(unsigned short s) {
    return __uint_as_float(((unsigned)s) << 16);
}

// ---------------- conv1: (128,3,32,32) -> (128,128,14,14), 5x5 stride 2 ----------------
__global__ void k_conv1(const float* __restrict__ x, const float* __restrict__ w,
                        float* __restrict__ h) {
    int idx = blockIdx.x * 256 + threadIdx.x;
    if (idx >= NB * AA * H1) return;
    int oy = idx % H1; int t = idx / H1;
    int oc = t % AA; int b = t / AA;
    float acc[14];
#pragma unroll
    for (int j = 0; j < 14; ++j) acc[j] = 0.f;
    const float* xb = x + b * 3072;
    const float* wc = w + oc * 75;
#pragma unroll
    for (int ic = 0; ic < 3; ++ic) {
#pragma unroll
        for (int ky = 0; ky < 5; ++ky) {
            const float* xr = xb + ic * 1024 + (2 * oy + ky) * 32;
            float row[32];
#pragma unroll
            for (int q = 0; q < 8; ++q) {
                float4 v = *reinterpret_cast<const float4*>(xr + q * 4);
                row[q * 4 + 0] = v.x; row[q * 4 + 1] = v.y;
                row[q * 4 + 2] = v.z; row[q * 4 + 3] = v.w;
            }
            float w0 = wc[ic * 25 + ky * 5 + 0];
            float w1 = wc[ic * 25 + ky * 5 + 1];
            float w2 = wc[ic * 25 + ky * 5 + 2];
            float w3 = wc[ic * 25 + ky * 5 + 3];
            float w4 = wc[ic * 25 + ky * 5 + 4];
#pragma unroll
            for (int ox = 0; ox < 14; ++ox) {
                float s = acc[ox];
                s = fmaf(row[2 * ox + 0], w0, s);
                s = fmaf(row[2 * ox + 1], w1, s);
                s = fmaf(row[2 * ox + 2], w2, s);
                s = fmaf(row[2 * ox + 3], w3, s);
                s = fmaf(row[2 * ox + 4], w4, s);
                acc[ox] = s;
            }
        }
    }
    float* out = h + (size_t)idx * 14;
#pragma unroll
    for (int ox = 0; ox < 14; ++ox) out[ox] = acc[ox];
}

// ---------------- bn1 stats: per-channel mean/var over (b, 14, 14) ----------------
__global__ void k_bnstats1(const float* __restrict__ h, const float* __restrict__ g,
                           const float* __restrict__ be, float* __restrict__ bn1) {
    int c = blockIdx.x;
    int tid = threadIdx.x;
    float s = 0.f, s2 = 0.f;
    for (int j = tid; j < NB * 196; j += 256) {
        int b = j / 196, hw = j % 196;
        float v = h[(b * AA + c) * 196 + hw];
        s += v; s2 += v * v;
    }
#pragma unroll
    for (int o = 32; o > 0; o >>= 1) { s += __shfl_down(s, o); s2 += __shfl_down(s2, o); }
    __shared__ float ls[4], lq[4];
    int lane = tid & 63, wid = tid >> 6;
    if (lane == 0) { ls[wid] = s; lq[wid] = s2; }
    __syncthreads();
    if (tid == 0) {
        s = ls[0] + ls[1] + ls[2] + ls[3];
        s2 = lq[0] + lq[1] + lq[2] + lq[3];
        const float n = (float)(NB * 196);
        float mu = s / n;
        float var = s2 / n - mu * mu;
        float sc = g[c] * rsqrtf(var + 1e-5f);
        bn1[c] = sc;
        bn1[AA + c] = be[c] - mu * sc;
    }
}

// ---------------- prep weights: prim_w [544][1152] f32 -> Ah/Al [576][1152] bf16 ------
__global__ void k_prepw(const float* __restrict__ w, unsigned short* __restrict__ Ah,
                        unsigned short* __restrict__ Al) {
    int t = blockIdx.x * 256 + threadIdx.x;
    if (t >= MG * (KG / 8)) return;
    int row = t / (KG / 8), seg = t % (KG / 8);
    alignas(16) unsigned short hi[8], lo[8];
    if (row < CH2) {
        const float* src = w + (size_t)row * KG + seg * 8;
#pragma unroll
        for (int j = 0; j < 8; ++j) {
            float v = src[j];
            unsigned short hh = f2bf(v);
            hi[j] = hh;
            lo[j] = f2bf(v - bf2f(hh));
        }
    } else {
#pragma unroll
        for (int j = 0; j < 8; ++j) { hi[j] = 0; lo[j] = 0; }
    }
    *reinterpret_cast<uint4*>(Ah + (size_t)row * KG + seg * 8) = *reinterpret_cast<const uint4*>(hi);
    *reinterpret_cast<uint4*>(Al + (size_t)row * KG + seg * 8) = *reinterpret_cast<const uint4*>(lo);
}

// ---------------- im2col + fused bn1+relu: h -> Bh/Bl [4608][1152] bf16 ---------------
// thread = (n, kseg): writes 8 contiguous bf16 of row n (coalesced 16B stores)
__global__ void k_im2col(const float* __restrict__ h, const float* __restrict__ bn1,
                         unsigned short* __restrict__ Bh, unsigned short* __restrict__ Bl) {
    int t = blockIdx.x * 256 + threadIdx.x;
    if (t >= NG * (KG / 8)) return;
    int n = t / (KG / 8), seg = t % (KG / 8);
    int b = n / 36, xy = n % 36;
    int oy = xy / 6, ox = xy % 6;
    const float* hb = h + (size_t)b * (AA * 196) + (2 * oy) * 14 + 2 * ox;
    alignas(16) unsigned short hi[8], lo[8];
#pragma unroll
    for (int j = 0; j < 8; ++j) {
        int k = seg * 8 + j;
        int ic = k / 9, kk = k - ic * 9;
        int ky = kk / 3, kx = kk - ky * 3;
        float v = hb[ic * 196 + ky * 14 + kx];
        v = fmaxf(fmaf(v, bn1[ic], bn1[AA + ic]), 0.f);
        unsigned short hh = f2bf(v);
        hi[j] = hh;
        lo[j] = f2bf(v - bf2f(hh));
    }
    *reinterpret_cast<uint4*>(Bh + (size_t)n * KG + seg * 8) = *reinterpret_cast<const uint4*>(hi);
    *reinterpret_cast<uint4*>(Bl + (size_t)n * KG + seg * 8) = *reinterpret_cast<const uint4*>(lo);
}

// ---------------- conv2 as split-bf16 MFMA GEMM: pcT[n][oc] = sum_k A[oc][k]*B[n][k] --
// grid (9, 72): 64x64 tile, BK=32, 4 waves (2x2), 12 MFMA/step (hi*hi + hi*lo + lo*hi)
__global__ __launch_bounds__(256, 4) void k_gemm(const unsigned short* __restrict__ Ah,
                                                 const unsigned short* __restrict__ Al,
                                                 const unsigned short* __restrict__ Bh,
                                                 const unsigned short* __restrict__ Bl,
                                                 float* __restrict__ pcT) {
    __shared__ alignas(16) unsigned short sAh[64][40], sAl[64][40];   // +8 pad: 2-way max
    __shared__ alignas(16) unsigned short sBh[64][40], sBl[64][40];   // 4*5120*2B = 40960B
    const int oc0 = blockIdx.x * 64;
    const int n0 = blockIdx.y * 64;
    const int tid = threadIdx.x;
    const int lane = tid & 63, wv = tid >> 6;
    const int wm = wv >> 1, wn = wv & 1;
    const int quad = lane >> 4, r16 = lane & 15;
    const int srow = tid >> 2, sseg = tid & 3;

    facc4 acc[2][2] = {};
    const size_t gA = (size_t)(oc0 + srow) * KG + sseg * 8;
    const size_t gB = (size_t)(n0 + srow) * KG + sseg * 8;

    for (int ks = 0; ks < KG / 32; ++ks) {
        const int k0 = ks * 32;
        // issue global loads early (overlap previous compute)
        uint4 vAh = *reinterpret_cast<const uint4*>(Ah + gA + k0);
        uint4 vAl = *reinterpret_cast<const uint4*>(Al + gA + k0);
        uint4 vBh = *reinterpret_cast<const uint4*>(Bh + gB + k0);
        uint4 vBl = *reinterpret_cast<const uint4*>(Bl + gB + k0);
        __syncthreads();   // previous step's reads done before overwrite
        *reinterpret_cast<uint4*>(&sAh[srow][sseg * 8]) = vAh;
        *reinterpret_cast<uint4*>(&sAl[srow][sseg * 8]) = vAl;
        *reinterpret_cast<uint4*>(&sBh[srow][sseg * 8]) = vBh;
        *reinterpret_cast<uint4*>(&sBl[srow][sseg * 8]) = vBl;
        __syncthreads();
        bfrag8 ah[2], al[2], bh[2], bl[2];
#pragma unroll
        for (int i = 0; i < 2; ++i) {
            ah[i] = *reinterpret_cast<const bfrag8*>(&sAh[wm * 32 + i * 16 + r16][quad * 8]);
            al[i] = *reinterpret_cast<const bfrag8*>(&sAl[wm * 32 + i * 16 + r16][quad * 8]);
            bh[i] = *reinterpret_cast<const bfrag8*>(&sBh[wn * 32 + i * 16 + r16][quad * 8]);
            bl[i] = *reinterpret_cast<const bfrag8*>(&sBl[wn * 32 + i * 16 + r16][quad * 8]);
        }
#pragma unroll
        for (int i = 0; i < 2; ++i)
#pragma unroll
            for (int j = 0; j < 2; ++j) {
                acc[i][j] = __builtin_amdgcn_mfma_f32_16x16x32_bf16(ah[i], bh[j], acc[i][j], 0, 0, 0);
                acc[i][j] = __builtin_amdgcn_mfma_f32_16x16x32_bf16(ah[i], bl[j], acc[i][j], 0, 0, 0);
                acc[i][j] = __builtin_amdgcn_mfma_f32_16x16x32_bf16(al[i], bh[j], acc[i][j], 0, 0, 0);
            }
    }
    // D mapping: col=lane&15 (n), row=quad*4+reg (oc) -> float4 store along contiguous oc
#pragma unroll
    for (int i = 0; i < 2; ++i) {
        int oc_base = oc0 + wm * 32 + i * 16 + quad * 4;
        if (oc_base >= CH2) continue;
#pragma unroll
        for (int j = 0; j < 2; ++j) {
            int n = n0 + wn * 32 + j * 16 + r16;
            *reinterpret_cast<facc4*>(pcT + (size_t)n * CH2 + oc_base) = acc[i][j];
        }
    }
}

// ---------------- bn stats on pcT[n][oc]: pose group i (cols i*16..+15), a (col 512+i) -
__global__ void k_bnstats2(const float* __restrict__ pcT,
                           const float* __restrict__ bna_g, const float* __restrict__ bna_b,
                           const float* __restrict__ bnp_g, const float* __restrict__ bnp_b,
                           float* __restrict__ bn2) {
    int blk = blockIdx.x;
    int tid = threadIdx.x;
    float s = 0.f, s2 = 0.f;
    if (blk < 32) {  // pose group i: sum over 4608 rows x 16 cols
        int i = blk;
        for (int j = tid; j < NG * 4; j += 256) {
            int row = j >> 2, q = j & 3;
            float4 v = *reinterpret_cast<const float4*>(pcT + (size_t)row * CH2 + i * 16 + q * 4);
            s += v.x + v.y + v.z + v.w;
            s2 += v.x * v.x + v.y * v.y + v.z * v.z + v.w * v.w;
        }
    } else {  // a channel i
        int i = blk - 32;
        for (int j = tid; j < NG; j += 256) {
            float v = pcT[(size_t)j * CH2 + BB * DD + i];
            s += v; s2 += v * v;
        }
    }
#pragma unroll
    for (int o = 32; o > 0; o >>= 1) { s += __shfl_down(s, o); s2 += __shfl_down(s2, o); }
    __shared__ float ls[4], lq[4];
    int lane = tid & 63, wid = tid >> 6;
    if (lane == 0) { ls[wid] = s; lq[wid] = s2; }
    __syncthreads();
    if (tid == 0) {
        s = ls[0] + ls[1] + ls[2] + ls[3];
        s2 = lq[0] + lq[1] + lq[2] + lq[3];
        if (blk < 32) {
            int i = blk;
            const float n = (float)(NB * DD * 36);
            float mu = s / n, var = s2 / n - mu * mu;
            float sc = bnp_g[i] * rsqrtf(var + 1e-5f);
            bn2[i] = sc; bn2[32 + i] = bnp_b[i] - mu * sc;
        } else {
            int i = blk - 32;
            const float n = (float)(NB * 36);
            float mu = s / n, var = s2 / n - mu * mu;
            float sc = bna_g[i] * rsqrtf(var + 1e-5f);
            bn2[64 + i] = sc; bn2[96 + i] = bna_b[i] - mu * sc;
        }
    }
}

// ---------------- transform: pcT -> poses_bn (b,n,16) and a_i (b,n) ----------------
__global__ void k_transform(const float* __restrict__ pcT, const float* __restrict__ bn2,
                            float* __restrict__ pose, float* __restrict__ ai) {
    int idx = blockIdx.x * 256 + threadIdx.x;  // (b, n_r) with n_r = i*36+xy
    if (idx >= NB * NN) return;
    int b = idx / NN, n = idx % NN;
    int i = n / 36, xy = n % 36;
    int row = b * 36 + xy;
    float sc = bn2[i], sh = bn2[32 + i];
    const float* src = pcT + (size_t)row * CH2 + i * 16;
    float* pd = pose + (size_t)idx * 16;
#pragma unroll
    for (int q = 0; q < 4; ++q) {
        float4 v = *reinterpret_cast<const float4*>(src + q * 4);
        v.x = fmaf(v.x, sc, sh); v.y = fmaf(v.y, sc, sh);
        v.z = fmaf(v.z, sc, sh); v.w = fmaf(v.w, sc, sh);
        *reinterpret_cast<float4*>(pd + q * 4) = v;
    }
    float va = fmaf(pcT[(size_t)row * CH2 + BB * DD + i], bn2[64 + i], bn2[96 + i]);
    ai[idx] = 1.f / (1.f + expf(-va));
}

// ---------------- VB stats: one wave per (b,c); Nj, S1[d]=Sum Ra*V, S2[d]=Sum Ra*V^2 ----
template <int FIRST>
__global__ void k_stats(const float* __restrict__ pose, const float* __restrict__ ai,
                        const float* __restrict__ R, const float* __restrict__ Wij,
                        float* __restrict__ Nj, float* __restrict__ S1, float* __restrict__ S2) {
    int bc = blockIdx.x * 4 + (threadIdx.x >> 6);   // 320 blocks * 4 waves = 1280
    int lane = threadIdx.x & 63;
    int c = bc % CC, b = bc / CC;
    float s0 = 0.f;
    float s1[16], s2[16];
#pragma unroll
    for (int k = 0; k < 16; ++k) { s1[k] = 0.f; s2[k] = 0.f; }
    for (int n = lane; n < NN; n += 64) {
        int i = n / 36, xy = n % 36;
        const float4* pp = reinterpret_cast<const float4*>(pose + ((size_t)b * NN + n) * 16);
        const float4* wp = reinterpret_cast<const float4*>(Wij + (((size_t)i * CC + c) * 36 + xy) * 16);
        alignas(16) float P[16], W[16];
        *reinterpret_cast<float4*>(&P[0])  = pp[0];
        *reinterpret_cast<float4*>(&P[4])  = pp[1];
        *reinterpret_cast<float4*>(&P[8])  = pp[2];
        *reinterpret_cast<float4*>(&P[12]) = pp[3];
        *reinterpret_cast<float4*>(&W[0])  = wp[0];
        *reinterpret_cast<float4*>(&W[4])  = wp[1];
        *reinterpret_cast<float4*>(&W[8])  = wp[2];
        *reinterpret_cast<float4*>(&W[12]) = wp[3];
        float wgt = ai[b * NN + n];
        if (FIRST) wgt *= 0.1f;
        else wgt *= R[((size_t)(b * CC + c)) * NN + n];
        s0 += wgt;
#pragma unroll
        for (int p = 0; p < 4; ++p) {
#pragma unroll
            for (int r = 0; r < 4; ++r) {
                float v = W[p * 4 + 0] * P[0 + r] + W[p * 4 + 1] * P[4 + r] +
                          W[p * 4 + 2] * P[8 + r] + W[p * 4 + 3] * P[12 + r];
                int d = p * 4 + r;
                float wv = wgt * v;
                s1[d] += wv;
                s2[d] = fmaf(wv, v, s2[d]);
            }
        }
    }
#pragma unroll
    for (int o = 32; o > 0; o >>= 1) {
        s0 += __shfl_down(s0, o);
#pragma unroll
        for (int k = 0; k < 16; ++k) {
            s1[k] += __shfl_down(s1[k], o);
            s2[k] += __shfl_down(s2[k], o);
        }
    }
    if (lane == 0) {
        Nj[bc] = s0 + 1e-8f;
#pragma unroll
        for (int k = 0; k < 16; ++k) { S1[bc * 16 + k] = s1[k]; S2[bc * 16 + k] = s2[k]; }
    }
}

// ---------------- digamma (args always >= 1.0 here) ----------------
__device__ __forceinline__ float digammaf_(float x) {
    float r = 0.f;
    while (x < 6.f) { r -= 1.f / x; x += 1.f; }
    float xi = 1.f / x;
    float xi2 = xi * xi;
    return r + logf(x) - 0.5f * xi -
           xi2 * (0.0833333333f - xi2 * (0.0083333333f - xi2 * 0.0039682540f));
}

// ---------------- expectations ----------------
template <int LOGITS>
__global__ void k_expect(const float* __restrict__ Nj, const float* __restrict__ S1,
                         const float* __restrict__ S2, float* __restrict__ m,
                         float* __restrict__ G, float* __restrict__ base,
                         float* __restrict__ logits) {
    int b = blockIdx.x;
    int c = threadIdx.x;  // 64 threads, 10 active
    __shared__ float alph[CC];
    float nj = 0.f;
    if (c < CC) {
        nj = Nj[b * CC + c];
        alph[c] = 1.f + nj;
    }
    __syncthreads();
    if (c < CC) {
        int bc = b * CC + c;
        float asum = 0.f;
#pragma unroll
        for (int k = 0; k < CC; ++k) asum += alph[k];
        float kappa = 1.f + nj;
        float nu = 17.f + nj;   // NU0 = D+1 = 17
        float S0 = nj - 1e-8f;
        float elnlam = 16.f * 0.69314718056f;  // D*ln2
        for (int d = 0; d < 16; ++d) {
            float s1 = S1[bc * 16 + d], s2v = S2[bc * 16 + d];
            float xbar = s1 / nj;
            float sig = (s2v - 2.f * xbar * s1 + xbar * xbar * S0) / nj;
            float Psi = 1.f + nj * sig + (nj / kappa) * xbar * xbar;
            elnlam += digammaf_(0.5f * (nu + 1.f - (float)(d + 1))) - logf(Psi);
            m[bc * 16 + d] = nj * xbar / kappa;
            G[bc * 16 + d] = 0.5f * nu / Psi;
        }
        float elnpi = digammaf_(1.f + nj) - digammaf_(asum);
        float lb = elnpi + 0.5f * elnlam;
        if (LOGITS) logits[bc] = lb;
        base[bc] = lb - 8.f * 1.83787706641f - 8.f / kappa;
    }
}

// ---------------- R update: per (b,n), softmax over c ----------------
__global__ void k_update(const float* __restrict__ pose, const float* __restrict__ Wij,
                         const float* __restrict__ m, const float* __restrict__ G,
                         const float* __restrict__ base, float* __restrict__ R) {
    int b = blockIdx.y;
    int n = blockIdx.x * 256 + threadIdx.x;
    __shared__ float sm[CC][16], sG[CC][16], sb[CC];
    for (int j = threadIdx.x; j < CC * 16; j += 256) {
        sm[j / 16][j % 16] = m[b * CC * 16 + j];
        sG[j / 16][j % 16] = G[b * CC * 16 + j];
    }
    if (threadIdx.x < CC) sb[threadIdx.x] = base[b * CC + threadIdx.x];
    __syncthreads();
    if (n >= NN) return;
    const float4* pp = reinterpret_cast<const float4*>(pose + ((size_t)b * NN + n) * 16);
    alignas(16) float P[16];
    *reinterpret_cast<float4*>(&P[0])  = pp[0];
    *reinterpret_cast<float4*>(&P[4])  = pp[1];
    *reinterpret_cast<float4*>(&P[8])  = pp[2];
    *reinterpret_cast<float4*>(&P[12]) = pp[3];
    int i = n / 36, xy = n % 36;
    float lnp[CC];
    float mx = -1e30f;
#pragma unroll
    for (int c = 0; c < CC; ++c) {
        const float4* wp = reinterpret_cast<const float4*>(Wij + (((size_t)i * CC + c) * 36 + xy) * 16);
        alignas(16) float W[16];
        *reinterpret_cast<float4*>(&W[0])  = wp[0];
        *reinterpret_cast<float4*>(&W[4])  = wp[1];
        *reinterpret_cast<float4*>(&W[8])  = wp[2];
        *reinterpret_cast<float4*>(&W[12]) = wp[3];
        float q = 0.f;
#pragma unroll
        for (int p = 0; p < 4; ++p) {
#pragma unroll
            for (int r = 0; r < 4; ++r) {
                float v = W[p * 4 + 0] * P[0 + r] + W[p * 4 + 1] * P[4 + r] +
                          W[p * 4 + 2] * P[8 + r] + W[p * 4 + 3] * P[12 + r];
                float dm = v - sm[c][p * 4 + r];
                q = fmaf(dm * dm, sG[c][p * 4 + r], q);
            }
        }
        lnp[c] = sb[c] - q;
        mx = fmaxf(mx, lnp[c]);
    }
    float ssum = 0.f;
#pragma unroll
    for (int c = 0; c < CC; ++c) { lnp[c] = expf(lnp[c] - mx); ssum += lnp[c]; }
    float inv = 1.f / ssum;
#pragma unroll
    for (int c = 0; c < CC; ++c) R[((size_t)(b * CC + c)) * NN + n] = lnp[c] * inv;
}

// ---------------- final: BN over batch per class + sigmoid ----------------
__global__ void k_final(const float* __restrict__ logits, float* __restrict__ out) {
    int c = blockIdx.x;      // 10 blocks
    int b = threadIdx.x;     // 128 threads
    float v = logits[b * CC + c];
    float s = v, s2 = v * v;
#pragma unroll
    for (int o = 32; o > 0; o >>= 1) { s += __shfl_down(s, o); s2 += __shfl_down(s2, o); }
    __shared__ float ls[2], lq[2];
    int lane = b & 63, wid = b >> 6;
    if (lane == 0) { ls[wid] = s; lq[wid] = s2; }
    __syncthreads();
    float mu = (ls[0] + ls[1]) * (1.f / 128.f);
    float var = (lq[0] + lq[1]) * (1.f / 128.f) - mu * mu;
    out[b * CC + c] = 1.f / (1.f + expf(-(v - mu) * rsqrtf(var + 1e-5f)));
}

extern "C" void kernel_launch(void* const* d_in, const int* in_sizes, int n_in,
                              void* d_out, int out_size, void* d_ws, size_t ws_size,
                              hipStream_t stream) {
    (void)in_sizes; (void)n_in; (void)out_size; (void)ws_size;
    const float* x       = (const float*)d_in[0];
    const float* conv1_w = (const float*)d_in[1];
    const float* bn1_g   = (const float*)d_in[2];
    const float* bn1_b   = (const float*)d_in[3];
    const float* prim_w  = (const float*)d_in[4];
    const float* bna_g   = (const float*)d_in[5];
    const float* bna_b   = (const float*)d_in[6];
    const float* bnp_g   = (const float*)d_in[7];
    const float* bnp_b   = (const float*)d_in[8];
    const float* Wij     = (const float*)d_in[9];

    float* ws = (float*)d_ws;
    float* h   = ws;                                          // 3,211,264 f32
    float* pcT = ws + 3211264;                                // 2,506,752 f32 [4608][544]
    unsigned short* Bh = (unsigned short*)(ws + 5718016);     // 5,308,416 bf16
    unsigned short* Bl = (unsigned short*)(ws + 8372224);     // 5,308,416 bf16
    unsigned short* Ahp = (unsigned short*)(ws + 11026432);   //   663,552 bf16
    unsigned short* Alp = (unsigned short*)(ws + 11358208);   //   663,552 bf16
    float* bn1    = ws + 11689984;   // 256
    float* bn2    = ws + 11690240;   // 128
    float* Nj     = ws + 11690368;   // 1,280
    float* S1     = ws + 11691648;   // 20,480
    float* S2     = ws + 11712128;   // 20,480
    float* m      = ws + 11732608;   // 20,480
    float* G      = ws + 11753088;   // 20,480
    float* base   = ws + 11773568;   // 1,280
    float* logits = ws + 11774848;   // 1,280
    // Aliases: Bh/Bl are dead after k_gemm; pose/ai/R reuse their space.
    float* pose = ws + 5718016;      // 2,359,296 f32 (inside Bh region)
    float* ai   = ws + 8372224;      //   147,456 f32 (inside Bl region)
    float* R    = ws + 8519680;      // 1,474,560 f32 (inside Bl region)
    float* out  = (float*)d_out;

    k_conv1<<<896, 256, 0, stream>>>(x, conv1_w, h);
    k_bnstats1<<<128, 256, 0, stream>>>(h, bn1_g, bn1_b, bn1);
    k_prepw<<<324, 256, 0, stream>>>(prim_w, Ahp, Alp);
    k_im2col<<<2592, 256, 0, stream>>>(h, bn1, Bh, Bl);
    k_gemm<<<dim3(9, 72), 256, 0, stream>>>(Ahp, Alp, Bh, Bl, pcT);
    k_bnstats2<<<64, 256, 0, stream>>>(pcT, bna_g, bna_b, bnp_g, bnp_b, bn2);
    k_transform<<<576, 256, 0, stream>>>(pcT, bn2, pose, ai);

    // routing iter 0 (R implicit = 1/C)
    k_stats<1><<<320, 256, 0, stream>>>(pose, ai, R, Wij, Nj, S1, S2);
    k_expect<0><<<128, 64, 0, stream>>>(Nj, S1, S2, m, G, base, logits);
    k_update<<<dim3(5, 128), 256, 0, stream>>>(pose, Wij, m, G, base, R);
    // iter 1
    k_stats<0><<<320, 256, 0, stream>>>(pose, ai, R, Wij, Nj, S1, S2);
    k_expect<0><<<128, 64, 0, stream>>>(Nj, S1, S2, m, G, base, logits);
    k_update<<<dim3(5, 128), 256, 0, stream>>>(pose, Wij, m, G, base, R);
    // iter 2 (stats + expectations only)
    k_stats<0><<<320, 256, 0, stream>>>(pose, ai, R, Wij, Nj, S1, S2);
    k_expect<1><<<128, 64, 0, stream>>>(Nj, S1, S2, m, G, base, logits);

    k_final<<<10, 128, 0, stream>>>(logits, out);
}

// Round 8
// 281.445 us; speedup vs baseline: 3.0265x; 1.1463x over previous
//
#include <hip/hip_runtime.h>
#include <hip/hip_bf16.h>

// Problem constants
#define NB 128     // batch
#define AA 128     // conv1 out channels
#define BB 32      // capsule types
#define CC 10      // classes
#define KK 6       // primary grid
#define DD 16      // pose dim
#define NN 1152    // B*K*K
#define H1 14      // conv1 out spatial
#define CH2 544    // B*D+B
#define NG 4608    // GEMM N = NB*36
#define KG 1152    // GEMM K = 128*9
#define MG 576     // GEMM M padded (544 -> 9*64)

typedef short bfrag8 __attribute__((ext_vector_type(8)));   // 8 bf16 (4 VGPRs)
typedef float facc4 __attribute__((ext_vector_type(4)));    // 4 fp32 acc

__device__ __forceinline__ unsigned short f2bf(float f) {   // RNE f32->bf16
    unsigned u = __float_as_uint(f);
    u += 0x7FFF + ((u >> 16) & 1);
    return (unsigned short)(u >> 16);
}
__device__ __forceinline__ float bf2f(unsigned short s) {
    return __uint_as_float(((unsigned)s) << 16);
}

// ---------------- conv1 (LDS-staged): (128,3,32,32) -> (128,128,14,14), 5x5 s2 --------
// grid (7, 128): blockIdx.x = output-row pair p (rows 2p,2p+1), blockIdx.y = b.
// 256 threads: thread = (oc = tid&127, ry = tid>>7). Input rows 4p..4p+6 + all
// 128x75 weights staged in LDS; input reads are wave-uniform broadcasts, weight
// reads stride-75 (11*oc mod 32 -> 2 lanes/bank, conflict-free).
__global__ __launch_bounds__(256, 3) void k_conv1(const float* __restrict__ x,
                                                  const float* __restrict__ w,
                                                  float* __restrict__ h) {
    __shared__ __align__(16) float sX[3][7][32];   //  2,688 B
    __shared__ float sWf[AA * 75];                 // 38,400 B
    const int p = blockIdx.x;
    const int b = blockIdx.y;
    const int tid = threadIdx.x;
    // stage weights (contiguous, coalesced)
    for (int j = tid; j < AA * 75; j += 256) sWf[j] = w[j];
    // stage input rows 4p..4p+6 of all 3 ics
    for (int j = tid; j < 3 * 7 * 32; j += 256) {
        int col = j & 31; int t2 = j >> 5; int row = t2 % 7; int ic = t2 / 7;
        sX[ic][row][col] = x[b * 3072 + ic * 1024 + (4 * p + row) * 32 + col];
    }
    __syncthreads();
    const int oc = tid & 127, ry = tid >> 7;
    const int r = 2 * p + ry;
    float acc[14];
#pragma unroll
    for (int j = 0; j < 14; ++j) acc[j] = 0.f;
    const float* wr = sWf + oc * 75;
#pragma unroll
    for (int ic = 0; ic < 3; ++ic) {
#pragma unroll
        for (int ky = 0; ky < 5; ++ky) {
            const float* xr = &sX[ic][2 * ry + ky][0];
            float row[32];
#pragma unroll
            for (int q = 0; q < 8; ++q) {
                float4 v = *reinterpret_cast<const float4*>(xr + q * 4);
                row[q * 4 + 0] = v.x; row[q * 4 + 1] = v.y;
                row[q * 4 + 2] = v.z; row[q * 4 + 3] = v.w;
            }
            float w0 = wr[ic * 25 + ky * 5 + 0];
            float w1 = wr[ic * 25 + ky * 5 + 1];
            float w2 = wr[ic * 25 + ky * 5 + 2];
            float w3 = wr[ic * 25 + ky * 5 + 3];
            float w4 = wr[ic * 25 + ky * 5 + 4];
#pragma unroll
            for (int ox = 0; ox < 14; ++ox) {
                float s = acc[ox];
                s = fmaf(row[2 * ox + 0], w0, s);
                s = fmaf(row[2 * ox + 1], w1, s);
                s = fmaf(row[2 * ox + 2], w2, s);
                s = fmaf(row[2 * ox + 3], w3, s);
                s = fmaf(row[2 * ox + 4], w4, s);
                acc[ox] = s;
            }
        }
    }
    float* out = h + ((size_t)(b * AA + oc) * 14 + r) * 14;
#pragma unroll
    for (int q = 0; q < 7; ++q)
        *reinterpret_cast<float2*>(out + q * 2) = make_float2(acc[q * 2], acc[q * 2 + 1]);
}

// ---------------- bn1 stats: per-channel mean/var over (b, 14, 14) ----------------
__global__ void k_bnstats1(const float* __restrict__ h, const float* __restrict__ g,
                           const float* __restrict__ be, float* __restrict__ bn1) {
    int c = blockIdx.x;
    int tid = threadIdx.x;
    float s = 0.f, s2 = 0.f;
    for (int j = tid; j < NB * 196; j += 256) {
        int b = j / 196, hw = j % 196;
        float v = h[(b * AA + c) * 196 + hw];
        s += v; s2 += v * v;
    }
#pragma unroll
    for (int o = 32; o > 0; o >>= 1) { s += __shfl_down(s, o); s2 += __shfl_down(s2, o); }
    __shared__ float ls[4], lq[4];
    int lane = tid & 63, wid = tid >> 6;
    if (lane == 0) { ls[wid] = s; lq[wid] = s2; }
    __syncthreads();
    if (tid == 0) {
        s = ls[0] + ls[1] + ls[2] + ls[3];
        s2 = lq[0] + lq[1] + lq[2] + lq[3];
        const float n = (float)(NB * 196);
        float mu = s / n;
        float var = s2 / n - mu * mu;
        float sc = g[c] * rsqrtf(var + 1e-5f);
        bn1[c] = sc;
        bn1[AA + c] = be[c] - mu * sc;
    }
}

// ---------------- prep weights: prim_w [544][1152] f32 -> Ah/Al [576][1152] bf16 ------
__global__ void k_prepw(const float* __restrict__ w, unsigned short* __restrict__ Ah,
                        unsigned short* __restrict__ Al) {
    int t = blockIdx.x * 256 + threadIdx.x;
    if (t >= MG * (KG / 8)) return;
    int row = t / (KG / 8), seg = t % (KG / 8);
    alignas(16) unsigned short hi[8], lo[8];
    if (row < CH2) {
        const float* src = w + (size_t)row * KG + seg * 8;
#pragma unroll
        for (int j = 0; j < 8; ++j) {
            float v = src[j];
            unsigned short hh = f2bf(v);
            hi[j] = hh;
            lo[j] = f2bf(v - bf2f(hh));
        }
    } else {
#pragma unroll
        for (int j = 0; j < 8; ++j) { hi[j] = 0; lo[j] = 0; }
    }
    *reinterpret_cast<uint4*>(Ah + (size_t)row * KG + seg * 8) = *reinterpret_cast<const uint4*>(hi);
    *reinterpret_cast<uint4*>(Al + (size_t)row * KG + seg * 8) = *reinterpret_cast<const uint4*>(lo);
}

// ---------------- im2col + fused bn1+relu: h -> Bh/Bl [4608][1152] bf16 ---------------
__global__ void k_im2col(const float* __restrict__ h, const float* __restrict__ bn1,
                         unsigned short* __restrict__ Bh, unsigned short* __restrict__ Bl) {
    int t = blockIdx.x * 256 + threadIdx.x;
    if (t >= NG * (KG / 8)) return;
    int n = t / (KG / 8), seg = t % (KG / 8);
    int b = n / 36, xy = n % 36;
    int oy = xy / 6, ox = xy % 6;
    const float* hb = h + (size_t)b * (AA * 196) + (2 * oy) * 14 + 2 * ox;
    alignas(16) unsigned short hi[8], lo[8];
#pragma unroll
    for (int j = 0; j < 8; ++j) {
        int k = seg * 8 + j;
        int ic = k / 9, kk = k - ic * 9;
        int ky = kk / 3, kx = kk - ky * 3;
        float v = hb[ic * 196 + ky * 14 + kx];
        v = fmaxf(fmaf(v, bn1[ic], bn1[AA + ic]), 0.f);
        unsigned short hh = f2bf(v);
        hi[j] = hh;
        lo[j] = f2bf(v - bf2f(hh));
    }
    *reinterpret_cast<uint4*>(Bh + (size_t)n * KG + seg * 8) = *reinterpret_cast<const uint4*>(hi);
    *reinterpret_cast<uint4*>(Bl + (size_t)n * KG + seg * 8) = *reinterpret_cast<const uint4*>(lo);
}

// ---------------- conv2 as split-bf16 MFMA GEMM: pcT[n][oc] = sum_k A[oc][k]*B[n][k] --
__global__ __launch_bounds__(256, 4) void k_gemm(const unsigned short* __restrict__ Ah,
                                                 const unsigned short* __restrict__ Al,
                                                 const unsigned short* __restrict__ Bh,
                                                 const unsigned short* __restrict__ Bl,
                                                 float* __restrict__ pcT) {
    __shared__ alignas(16) unsigned short sAh[64][40], sAl[64][40];
    __shared__ alignas(16) unsigned short sBh[64][40], sBl[64][40];
    const int oc0 = blockIdx.x * 64;
    const int n0 = blockIdx.y * 64;
    const int tid = threadIdx.x;
    const int lane = tid & 63, wv = tid >> 6;
    const int wm = wv >> 1, wn = wv & 1;
    const int quad = lane >> 4, r16 = lane & 15;
    const int srow = tid >> 2, sseg = tid & 3;

    facc4 acc[2][2] = {};
    const size_t gA = (size_t)(oc0 + srow) * KG + sseg * 8;
    const size_t gB = (size_t)(n0 + srow) * KG + sseg * 8;

    for (int ks = 0; ks < KG / 32; ++ks) {
        const int k0 = ks * 32;
        uint4 vAh = *reinterpret_cast<const uint4*>(Ah + gA + k0);
        uint4 vAl = *reinterpret_cast<const uint4*>(Al + gA + k0);
        uint4 vBh = *reinterpret_cast<const uint4*>(Bh + gB + k0);
        uint4 vBl = *reinterpret_cast<const uint4*>(Bl + gB + k0);
        __syncthreads();
        *reinterpret_cast<uint4*>(&sAh[srow][sseg * 8]) = vAh;
        *reinterpret_cast<uint4*>(&sAl[srow][sseg * 8]) = vAl;
        *reinterpret_cast<uint4*>(&sBh[srow][sseg * 8]) = vBh;
        *reinterpret_cast<uint4*>(&sBl[srow][sseg * 8]) = vBl;
        __syncthreads();
        bfrag8 ah[2], al[2], bh[2], bl[2];
#pragma unroll
        for (int i = 0; i < 2; ++i) {
            ah[i] = *reinterpret_cast<const bfrag8*>(&sAh[wm * 32 + i * 16 + r16][quad * 8]);
            al[i] = *reinterpret_cast<const bfrag8*>(&sAl[wm * 32 + i * 16 + r16][quad * 8]);
            bh[i] = *reinterpret_cast<const bfrag8*>(&sBh[wn * 32 + i * 16 + r16][quad * 8]);
            bl[i] = *reinterpret_cast<const bfrag8*>(&sBl[wn * 32 + i * 16 + r16][quad * 8]);
        }
#pragma unroll
        for (int i = 0; i < 2; ++i)
#pragma unroll
            for (int j = 0; j < 2; ++j) {
                acc[i][j] = __builtin_amdgcn_mfma_f32_16x16x32_bf16(ah[i], bh[j], acc[i][j], 0, 0, 0);
                acc[i][j] = __builtin_amdgcn_mfma_f32_16x16x32_bf16(ah[i], bl[j], acc[i][j], 0, 0, 0);
                acc[i][j] = __builtin_amdgcn_mfma_f32_16x16x32_bf16(al[i], bh[j], acc[i][j], 0, 0, 0);
            }
    }
#pragma unroll
    for (int i = 0; i < 2; ++i) {
        int oc_base = oc0 + wm * 32 + i * 16 + quad * 4;
        if (oc_base >= CH2) continue;
#pragma unroll
        for (int j = 0; j < 2; ++j) {
            int n = n0 + wn * 32 + j * 16 + r16;
            *reinterpret_cast<facc4*>(pcT + (size_t)n * CH2 + oc_base) = acc[i][j];
        }
    }
}

// ---------------- bn stats on pcT[n][oc] ----------------
__global__ void k_bnstats2(const float* __restrict__ pcT,
                           const float* __restrict__ bna_g, const float* __restrict__ bna_b,
                           const float* __restrict__ bnp_g, const float* __restrict__ bnp_b,
                           float* __restrict__ bn2) {
    int blk = blockIdx.x;
    int tid = threadIdx.x;
    float s = 0.f, s2 = 0.f;
    if (blk < 32) {
        int i = blk;
        for (int j = tid; j < NG * 4; j += 256) {
            int row = j >> 2, q = j & 3;
            float4 v = *reinterpret_cast<const float4*>(pcT + (size_t)row * CH2 + i * 16 + q * 4);
            s += v.x + v.y + v.z + v.w;
            s2 += v.x * v.x + v.y * v.y + v.z * v.z + v.w * v.w;
        }
    } else {
        int i = blk - 32;
        for (int j = tid; j < NG; j += 256) {
            float v = pcT[(size_t)j * CH2 + BB * DD + i];
            s += v; s2 += v * v;
        }
    }
#pragma unroll
    for (int o = 32; o > 0; o >>= 1) { s += __shfl_down(s, o); s2 += __shfl_down(s2, o); }
    __shared__ float ls[4], lq[4];
    int lane = tid & 63, wid = tid >> 6;
    if (lane == 0) { ls[wid] = s; lq[wid] = s2; }
    __syncthreads();
    if (tid == 0) {
        s = ls[0] + ls[1] + ls[2] + ls[3];
        s2 = lq[0] + lq[1] + lq[2] + lq[3];
        if (blk < 32) {
            int i = blk;
            const float n = (float)(NB * DD * 36);
            float mu = s / n, var = s2 / n - mu * mu;
            float sc = bnp_g[i] * rsqrtf(var + 1e-5f);
            bn2[i] = sc; bn2[32 + i] = bnp_b[i] - mu * sc;
        } else {
            int i = blk - 32;
            const float n = (float)(NB * 36);
            float mu = s / n, var = s2 / n - mu * mu;
            float sc = bna_g[i] * rsqrtf(var + 1e-5f);
            bn2[64 + i] = sc; bn2[96 + i] = bna_b[i] - mu * sc;
        }
    }
}

// ---------------- transform: pcT -> poses_bn (b,n,16) and a_i (b,n) ----------------
__global__ void k_transform(const float* __restrict__ pcT, const float* __restrict__ bn2,
                            float* __restrict__ pose, float* __restrict__ ai) {
    int idx = blockIdx.x * 256 + threadIdx.x;
    if (idx >= NB * NN) return;
    int b = idx / NN, n = idx % NN;
    int i = n / 36, xy = n % 36;
    int row = b * 36 + xy;
    float sc = bn2[i], sh = bn2[32 + i];
    const float* src = pcT + (size_t)row * CH2 + i * 16;
    float* pd = pose + (size_t)idx * 16;
#pragma unroll
    for (int q = 0; q < 4; ++q) {
        float4 v = *reinterpret_cast<const float4*>(src + q * 4);
        v.x = fmaf(v.x, sc, sh); v.y = fmaf(v.y, sc, sh);
        v.z = fmaf(v.z, sc, sh); v.w = fmaf(v.w, sc, sh);
        *reinterpret_cast<float4*>(pd + q * 4) = v;
    }
    float va = fmaf(pcT[(size_t)row * CH2 + BB * DD + i], bn2[64 + i], bn2[96 + i]);
    ai[idx] = 1.f / (1.f + expf(-va));
}

// ---------------- VB stats: one wave per (b,c) ----------------
template <int FIRST>
__global__ void k_stats(const float* __restrict__ pose, const float* __restrict__ ai,
                        const float* __restrict__ R, const float* __restrict__ Wij,
                        float* __restrict__ Nj, float* __restrict__ S1, float* __restrict__ S2) {
    int bc = blockIdx.x * 4 + (threadIdx.x >> 6);
    int lane = threadIdx.x & 63;
    int c = bc % CC, b = bc / CC;
    float s0 = 0.f;
    float s1[16], s2[16];
#pragma unroll
    for (int k = 0; k < 16; ++k) { s1[k] = 0.f; s2[k] = 0.f; }
    for (int n = lane; n < NN; n += 64) {
        int i = n / 36, xy = n % 36;
        const float4* pp = reinterpret_cast<const float4*>(pose + ((size_t)b * NN + n) * 16);
        const float4* wp = reinterpret_cast<const float4*>(Wij + (((size_t)i * CC + c) * 36 + xy) * 16);
        alignas(16) float P[16], W[16];
        *reinterpret_cast<float4*>(&P[0])  = pp[0];
        *reinterpret_cast<float4*>(&P[4])  = pp[1];
        *reinterpret_cast<float4*>(&P[8])  = pp[2];
        *reinterpret_cast<float4*>(&P[12]) = pp[3];
        *reinterpret_cast<float4*>(&W[0])  = wp[0];
        *reinterpret_cast<float4*>(&W[4])  = wp[1];
        *reinterpret_cast<float4*>(&W[8])  = wp[2];
        *reinterpret_cast<float4*>(&W[12]) = wp[3];
        float wgt = ai[b * NN + n];
        if (FIRST) wgt *= 0.1f;
        else wgt *= R[((size_t)(b * CC + c)) * NN + n];
        s0 += wgt;
#pragma unroll
        for (int p = 0; p < 4; ++p) {
#pragma unroll
            for (int r = 0; r < 4; ++r) {
                float v = W[p * 4 + 0] * P[0 + r] + W[p * 4 + 1] * P[4 + r] +
                          W[p * 4 + 2] * P[8 + r] + W[p * 4 + 3] * P[12 + r];
                int d = p * 4 + r;
                float wv = wgt * v;
                s1[d] += wv;
                s2[d] = fmaf(wv, v, s2[d]);
            }
        }
    }
#pragma unroll
    for (int o = 32; o > 0; o >>= 1) {
        s0 += __shfl_down(s0, o);
#pragma unroll
        for (int k = 0; k < 16; ++k) {
            s1[k] += __shfl_down(s1[k], o);
            s2[k] += __shfl_down(s2[k], o);
        }
    }
    if (lane == 0) {
        Nj[bc] = s0 + 1e-8f;
#pragma unroll
        for (int k = 0; k < 16; ++k) { S1[bc * 16 + k] = s1[k]; S2[bc * 16 + k] = s2[k]; }
    }
}

// ---------------- digamma (args always >= 1.0 here) ----------------
__device__ __forceinline__ float digammaf_(float x) {
    float r = 0.f;
    while (x < 6.f) { r -= 1.f / x; x += 1.f; }
    float xi = 1.f / x;
    float xi2 = xi * xi;
    return r + logf(x) - 0.5f * xi -
           xi2 * (0.0833333333f - xi2 * (0.0083333333f - xi2 * 0.0039682540f));
}

// ---------------- expectations ----------------
template <int LOGITS>
__global__ void k_expect(const float* __restrict__ Nj, const float* __restrict__ S1,
                         const float* __restrict__ S2, float* __restrict__ m,
                         float* __restrict__ G, float* __restrict__ base,
                         float* __restrict__ logits) {
    int b = blockIdx.x;
    int c = threadIdx.x;
    __shared__ float alph[CC];
    float nj = 0.f;
    if (c < CC) {
        nj = Nj[b * CC + c];
        alph[c] = 1.f + nj;
    }
    __syncthreads();
    if (c < CC) {
        int bc = b * CC + c;
        float asum = 0.f;
#pragma unroll
        for (int k = 0; k < CC; ++k) asum += alph[k];
        float kappa = 1.f + nj;
        float nu = 17.f + nj;
        float S0 = nj - 1e-8f;
        float elnlam = 16.f * 0.69314718056f;
        for (int d = 0; d < 16; ++d) {
            float s1 = S1[bc * 16 + d], s2v = S2[bc * 16 + d];
            float xbar = s1 / nj;
            float sig = (s2v - 2.f * xbar * s1 + xbar * xbar * S0) / nj;
            float Psi = 1.f + nj * sig + (nj / kappa) * xbar * xbar;
            elnlam += digammaf_(0.5f * (nu + 1.f - (float)(d + 1))) - logf(Psi);
            m[bc * 16 + d] = nj * xbar / kappa;
            G[bc * 16 + d] = 0.5f * nu / Psi;
        }
        float elnpi = digammaf_(1.f + nj) - digammaf_(asum);
        float lb = elnpi + 0.5f * elnlam;
        if (LOGITS) logits[bc] = lb;
        base[bc] = lb - 8.f * 1.83787706641f - 8.f / kappa;
    }
}

// ---------------- R update: per (b,n), softmax over c ----------------
__global__ void k_update(const float* __restrict__ pose, const float* __restrict__ Wij,
                         const float* __restrict__ m, const float* __restrict__ G,
                         const float* __restrict__ base, float* __restrict__ R) {
    int b = blockIdx.y;
    int n = blockIdx.x * 256 + threadIdx.x;
    __shared__ float sm[CC][16], sG[CC][16], sb[CC];
    for (int j = threadIdx.x; j < CC * 16; j += 256) {
        sm[j / 16][j % 16] = m[b * CC * 16 + j];
        sG[j / 16][j % 16] = G[b * CC * 16 + j];
    }
    if (threadIdx.x < CC) sb[threadIdx.x] = base[b * CC + threadIdx.x];
    __syncthreads();
    if (n >= NN) return;
    const float4* pp = reinterpret_cast<const float4*>(pose + ((size_t)b * NN + n) * 16);
    alignas(16) float P[16];
    *reinterpret_cast<float4*>(&P[0])  = pp[0];
    *reinterpret_cast<float4*>(&P[4])  = pp[1];
    *reinterpret_cast<float4*>(&P[8])  = pp[2];
    *reinterpret_cast<float4*>(&P[12]) = pp[3];
    int i = n / 36, xy = n % 36;
    float lnp[CC];
    float mx = -1e30f;
#pragma unroll
    for (int c = 0; c < CC; ++c) {
        const float4* wp = reinterpret_cast<const float4*>(Wij + (((size_t)i * CC + c) * 36 + xy) * 16);
        alignas(16) float W[16];
        *reinterpret_cast<float4*>(&W[0])  = wp[0];
        *reinterpret_cast<float4*>(&W[4])  = wp[1];
        *reinterpret_cast<float4*>(&W[8])  = wp[2];
        *reinterpret_cast<float4*>(&W[12]) = wp[3];
        float q = 0.f;
#pragma unroll
        for (int p = 0; p < 4; ++p) {
#pragma unroll
            for (int r = 0; r < 4; ++r) {
                float v = W[p * 4 + 0] * P[0 + r] + W[p * 4 + 1] * P[4 + r] +
                          W[p * 4 + 2] * P[8 + r] + W[p * 4 + 3] * P[12 + r];
                float dm = v - sm[c][p * 4 + r];
                q = fmaf(dm * dm, sG[c][p * 4 + r], q);
            }
        }
        lnp[c] = sb[c] - q;
        mx = fmaxf(mx, lnp[c]);
    }
    float ssum = 0.f;
#pragma unroll
    for (int c = 0; c < CC; ++c) { lnp[c] = expf(lnp[c] - mx); ssum += lnp[c]; }
    float inv = 1.f / ssum;
#pragma unroll
    for (int c = 0; c < CC; ++c) R[((size_t)(b * CC + c)) * NN + n] = lnp[c] * inv;
}

// ---------------- final: BN over batch per class + sigmoid ----------------
__global__ void k_final(const float* __restrict__ logits, float* __restrict__ out) {
    int c = blockIdx.x;
    int b = threadIdx.x;
    float v = logits[b * CC + c];
    float s = v, s2 = v * v;
#pragma unroll
    for (int o = 32; o > 0; o >>= 1) { s += __shfl_down(s, o); s2 += __shfl_down(s2, o); }
    __shared__ float ls[2], lq[2];
    int lane = b & 63, wid = b >> 6;
    if (lane == 0) { ls[wid] = s; lq[wid] = s2; }
    __syncthreads();
    float mu = (ls[0] + ls[1]) * (1.f / 128.f);
    float var = (lq[0] + lq[1]) * (1.f / 128.f) - mu * mu;
    out[b * CC + c] = 1.f / (1.f + expf(-(v - mu) * rsqrtf(var + 1e-5f)));
}

extern "C" void kernel_launch(void* const* d_in, const int* in_sizes, int n_in,
                              void* d_out, int out_size, void* d_ws, size_t ws_size,
                              hipStream_t stream) {
    (void)in_sizes; (void)n_in; (void)out_size; (void)ws_size;
    const float* x       = (const float*)d_in[0];
    const float* conv1_w = (const float*)d_in[1];
    const float* bn1_g   = (const float*)d_in[2];
    const float* bn1_b   = (const float*)d_in[3];
    const float* prim_w  = (const float*)d_in[4];
    const float* bna_g   = (const float*)d_in[5];
    const float* bna_b   = (const float*)d_in[6];
    const float* bnp_g   = (const float*)d_in[7];
    const float* bnp_b   = (const float*)d_in[8];
    const float* Wij     = (const float*)d_in[9];

    float* ws = (float*)d_ws;
    float* h   = ws;                                          // 3,211,264 f32
    float* pcT = ws + 3211264;                                // 2,506,752 f32 [4608][544]
    unsigned short* Bh = (unsigned short*)(ws + 5718016);     // 5,308,416 bf16
    unsigned short* Bl = (unsigned short*)(ws + 8372224);     // 5,308,416 bf16
    unsigned short* Ahp = (unsigned short*)(ws + 11026432);   //   663,552 bf16
    unsigned short* Alp = (unsigned short*)(ws + 11358208);   //   663,552 bf16
    float* bn1    = ws + 11689984;   // 256
    float* bn2    = ws + 11690240;   // 128
    float* Nj     = ws + 11690368;   // 1,280
    float* S1     = ws + 11691648;   // 20,480
    float* S2     = ws + 11712128;   // 20,480
    float* m      = ws + 11732608;   // 20,480
    float* G      = ws + 11753088;   // 20,480
    float* base   = ws + 11773568;   // 1,280
    float* logits = ws + 11774848;   // 1,280
    // Aliases: Bh/Bl are dead after k_gemm; pose/ai/R reuse their space.
    float* pose = ws + 5718016;      // 2,359,296 f32 (inside Bh region)
    float* ai   = ws + 8372224;      //   147,456 f32 (inside Bl region)
    float* R    = ws + 8519680;      // 1,474,560 f32 (inside Bl region)
    float* out  = (float*)d_out;

    k_conv1<<<dim3(7, 128), 256, 0, stream>>>(x, conv1_w, h);
    k_bnstats1<<<128, 256, 0, stream>>>(h, bn1_g, bn1_b, bn1);
    k_prepw<<<324, 256, 0, stream>>>(prim_w, Ahp, Alp);
    k_im2col<<<2592, 256, 0, stream>>>(h, bn1, Bh, Bl);
    k_gemm<<<dim3(9, 72), 256, 0, stream>>>(Ahp, Alp, Bh, Bl, pcT);
    k_bnstats2<<<64, 256, 0, stream>>>(pcT, bna_g, bna_b, bnp_g, bnp_b, bn2);
    k_transform<<<576, 256, 0, stream>>>(pcT, bn2, pose, ai);

    // routing iter 0 (R implicit = 1/C)
    k_stats<1><<<320, 256, 0, stream>>>(pose, ai, R, Wij, Nj, S1, S2);
    k_expect<0><<<128, 64, 0, stream>>>(Nj, S1, S2, m, G, base, logits);
    k_update<<<dim3(5, 128), 256, 0, stream>>>(pose, Wij, m, G, base, R);
    // iter 1
    k_stats<0><<<320, 256, 0, stream>>>(pose, ai, R, Wij, Nj, S1, S2);
    k_expect<0><<<128, 64, 0, stream>>>(Nj, S1, S2, m, G, base, logits);
    k_update<<<dim3(5, 128), 256, 0, stream>>>(pose, Wij, m, G, base, R);
    // iter 2 (stats + expectations only)
    k_stats<0><<<320, 256, 0, stream>>>(pose, ai, R, Wij, Nj, S1, S2);
    k_expect<1><<<128, 64, 0, stream>>>(Nj, S1, S2, m, G, base, logits);

    k_final<<<10, 128, 0, stream>>>(logits, out);
}